// Round 2
// 1110.932 us; speedup vs baseline: 1.0754x; 1.0754x over previous
//
#include <hip/hip_runtime.h>
#include <math.h>

typedef short v8s __attribute__((ext_vector_type(8)));
typedef float v16f __attribute__((ext_vector_type(16)));

// fp32 -> bf16 (RNE)
__device__ inline unsigned short f2bf(float f) {
    union { float f; unsigned u; } c; c.f = f;
    unsigned r = (c.u + 0x7fffu + ((c.u >> 16) & 1u)) >> 16;
    return (unsigned short)r;
}

// =====================================================================
// fusion: out = m * sepconv5(feat, kv, kh) + (1-m) * feat   (fp32)
// =====================================================================
__global__ __launch_bounds__(256) void fusion_kernel(
        const float* __restrict__ feat, const float* __restrict__ kv,
        const float* __restrict__ kh, const float* __restrict__ m,
        float* __restrict__ out, int C, int H, int W, int total) {
    int idx = blockIdx.x * 256 + threadIdx.x;
    if (idx >= total) return;
    int x = idx % W;
    int y = (idx / W) % H;
    int b = idx / (W * H * C);
    int hw = H * W;
    int pix = y * W + x;
    float mv = m[b * hw + pix];
    float kvv[5], khv[5];
#pragma unroll
    for (int i = 0; i < 5; i++) {
        kvv[i] = kv[(b * 5 + i) * hw + pix];
        khv[i] = kh[(b * 5 + i) * hw + pix];
    }
    int cx[5], cy[5];
#pragma unroll
    for (int j = 0; j < 5; j++) {
        int xx = x + j - 2; cx[j] = xx < 0 ? 0 : (xx >= W ? W - 1 : xx);
        int yy = y + j - 2; cy[j] = yy < 0 ? 0 : (yy >= H ? H - 1 : yy);
    }
    const float* fp = feat + (size_t)(idx - pix);
    float s = 0.f;
#pragma unroll
    for (int i = 0; i < 5; i++) {
        const float* rp = fp + cy[i] * W;
        float h = 0.f;
#pragma unroll
        for (int j = 0; j < 5; j++) h += rp[cx[j]] * khv[j];
        s += kvv[i] * h;
    }
    float fv = feat[idx];
    out[idx] = mv * s + (1.f - mv) * fv;
}

// =====================================================================
// NCHW fp32 -> NHWC bf16 transpose. One block per (y, b).
// =====================================================================
__global__ __launch_bounds__(256) void nchw_to_nhwc_bf16(
        const float* __restrict__ in, unsigned short* __restrict__ out,
        int C, int H, int W, int lw, int lc2) {
    extern __shared__ unsigned short sm_t[];
    const int y = blockIdx.x, b = blockIdx.y;
    const int Cp = C + 8;
    const int tid = threadIdx.x;
    for (int i = tid; i < C * W; i += 256) {
        int x = i & (W - 1), c = i >> lw;
        float v = in[(((size_t)b * C + c) * H + y) * W + x];
        sm_t[x * Cp + c] = f2bf(v);
    }
    __syncthreads();
    const unsigned* s32 = (const unsigned*)sm_t;
    unsigned* o32 = (unsigned*)(out + (((size_t)b * H + y) * W) * C);
    const int n32 = (W * C) >> 1;
    for (int i = tid; i < n32; i += 256) {
        int x = i >> lc2;
        int c2 = i - (x << lc2);
        o32[i] = s32[x * (Cp >> 1) + c2];
    }
}

// =====================================================================
// Repack [Cin][Cout][3][3] fp32 -> MFMA-fragment-ordered bf16:
//   [t][co>>5][ci>>4][ (kg=((ci>>3)&1))*32 + (co&31) ][ci&7]
// i.e. per (tap, 32-co block, 16-ci block): 512 contiguous shorts laid
// out so that lane = kg*32+n reads its v8s at base + lane*16B --
// a single fully-coalesced 1KiB load per wave (was a 64-line gather).
// flip=1: tap t stores source index 8-t (deconv-as-conv, stride 1).
// =====================================================================
__global__ __launch_bounds__(256) void repack_w_frag(
        const float* __restrict__ w, unsigned short* __restrict__ wk,
        int Cin, int Cout, int flip) {
    int idx = blockIdx.x * 256 + threadIdx.x;
    if (idx >= Cin * Cout) return;
    int ci = idx / Cout, co = idx - ci * Cout;
    const float* src = w + (size_t)idx * 9;
    const int nCb = Cout >> 5, nH = Cin >> 4;
    const size_t inner = (size_t)((((ci >> 3) & 1) * 32 + (co & 31)) * 8 + (ci & 7));
#pragma unroll
    for (int k = 0; k < 9; k++) {
        int t = flip ? (8 - k) : k;
        size_t blk = ((size_t)t * nCb + (co >> 5)) * nH + (ci >> 4);
        wk[(blk << 9) + inner] = f2bf(src[k]);
    }
}

// =====================================================================
// 3x3 conv (pad 1, pre-flipped weights) MFMA implicit GEMM + ReLU.
// X: [B,H,W,Cin] bf16. Wk: fragment-ordered bf16 (repack_w_frag).
// out: [B,H,W,Cout] bf16.
// Block = 4 waves (2x2); tile M=128 co x N=128 px. Wave 64x64.
// =====================================================================
template<int W, int TH, int LW>
__global__ __launch_bounds__(256) void conv3x3_mfma(
        const unsigned short* __restrict__ X,
        const unsigned short* __restrict__ Wk,
        unsigned short* __restrict__ out, int Cin, int Cout, int H) {
    constexpr int TP = (TH + 2) * (W + 2);
    __shared__ unsigned short sB[TP * 40];
    const int tid = threadIdx.x;
    const int lane = tid & 63, wv = tid >> 6;
    const int wm = wv >> 1, wn = wv & 1;
    const int y0 = blockIdx.x * TH;
    const int coB = blockIdx.y * 128 + wm * 64;
    const int b = blockIdx.z;
    const int n = lane & 31, kg = lane >> 5;
    const int p0 = wn * 64 + n, p1 = p0 + 32;
    const int r0 = p0 >> LW, c0 = p0 & (W - 1);
    const int r1 = p1 >> LW, c1 = p1 & (W - 1);
    const int bo0 = (r0 * (W + 2) + c0) * 40 + kg * 8;
    const int bo1 = (r1 * (W + 2) + c1) * 40 + kg * 8;
    v16f acc00 = {}, acc01 = {}, acc10 = {}, acc11 = {};
    // fragment-ordered weight addressing
    const size_t cbStride = (size_t)(Cin >> 4) << 9;          // shorts per 32-co block
    const size_t tStride  = (size_t)(Cout >> 5) * cbStride;   // shorts per tap
    const unsigned short* Af = Wk + (size_t)(coB >> 5) * cbStride + (lane << 3);
    const unsigned short* Xb = X + (size_t)b * H * W * Cin;

    for (int ci0 = 0; ci0 < Cin; ci0 += 32) {
        for (int i = tid; i < TP * 4; i += 256) {
            int pix = i >> 2, part = i & 3;
            int py = pix / (W + 2), px = pix - py * (W + 2);
            int gy = y0 + py - 1, gx = px - 1;
            uint4 v = make_uint4(0u, 0u, 0u, 0u);
            if (gy >= 0 && gy < H && (unsigned)gx < (unsigned)W)
                v = *(const uint4*)(Xb + ((size_t)(gy * W + gx)) * Cin + ci0 + part * 8);
            *(uint4*)(sB + pix * 40 + part * 8) = v;
        }
        __syncthreads();
#pragma unroll
        for (int t = 0; t < 9; t++) {
            const int ky = t / 3, kx = t - ky * 3;
            const int toff = (ky * (W + 2) + kx) * 40;
#pragma unroll
            for (int kh = 0; kh < 2; kh++) {
                const unsigned short* ap =
                    Af + (size_t)t * tStride + (size_t)(((ci0 >> 4) + kh) << 9);
                v8s A0 = *(const v8s*)(ap);
                v8s A1 = *(const v8s*)(ap + cbStride);
                v8s B0 = *(const v8s*)(sB + bo0 + toff + kh * 16);
                v8s B1 = *(const v8s*)(sB + bo1 + toff + kh * 16);
                acc00 = __builtin_amdgcn_mfma_f32_32x32x16_bf16(A0, B0, acc00, 0, 0, 0);
                acc01 = __builtin_amdgcn_mfma_f32_32x32x16_bf16(A0, B1, acc01, 0, 0, 0);
                acc10 = __builtin_amdgcn_mfma_f32_32x32x16_bf16(A1, B0, acc10, 0, 0, 0);
                acc11 = __builtin_amdgcn_mfma_f32_32x32x16_bf16(A1, B1, acc11, 0, 0, 0);
            }
        }
        __syncthreads();
    }
    // C/D: col=lane&31 -> pixel, row r -> co = base + (r&3) + 8*(r>>2) + 4*kg
    unsigned short* ob = out + (size_t)b * H * W * Cout;
#pragma unroll
    for (int sm = 0; sm < 2; sm++) {
        v16f a0 = sm ? acc10 : acc00;
        v16f a1 = sm ? acc11 : acc01;
        const int cobase = coB + sm * 32 + 4 * kg;
        unsigned short* q0p = ob + ((size_t)((y0 + r0) * W + c0)) * Cout + cobase;
        unsigned short* q1p = ob + ((size_t)((y0 + r1) * W + c1)) * Cout + cobase;
#pragma unroll
        for (int r2 = 0; r2 < 4; r2++) {
            ushort4 q0, q1; float v;
            v = a0[4 * r2 + 0]; v = v > 0.f ? v : 0.f; q0.x = f2bf(v);
            v = a0[4 * r2 + 1]; v = v > 0.f ? v : 0.f; q0.y = f2bf(v);
            v = a0[4 * r2 + 2]; v = v > 0.f ? v : 0.f; q0.z = f2bf(v);
            v = a0[4 * r2 + 3]; v = v > 0.f ? v : 0.f; q0.w = f2bf(v);
            *(ushort4*)(q0p + 8 * r2) = q0;
            v = a1[4 * r2 + 0]; v = v > 0.f ? v : 0.f; q1.x = f2bf(v);
            v = a1[4 * r2 + 1]; v = v > 0.f ? v : 0.f; q1.y = f2bf(v);
            v = a1[4 * r2 + 2]; v = v > 0.f ? v : 0.f; q1.z = f2bf(v);
            v = a1[4 * r2 + 3]; v = v > 0.f ? v : 0.f; q1.w = f2bf(v);
            *(ushort4*)(q1p + 8 * r2) = q1;
        }
    }
}

// =====================================================================
// stride-2 deconv (k=3,p=1,op=1) as 4 parity convs on MFMA + ReLU.
// out(2Y+py, 2X+px): ky set = {1} if py==0 else {2 (dy=0), 0 (dy=1)}.
// X: [B,Hin,W,Cin] NHWC bf16. Wk: fragment-ordered bf16 UNflipped.
// out: [B,Cout,2Hin,2W] fp32 NCHW. Block = NWM*NWN waves; wave:
// M=64 co, N=32 px strip (TH rows x W), 4 parities (8 v16f accs).
// =====================================================================
template<int W, int TH, int NWN, int NWM, int LW>
__global__ __launch_bounds__(256) void deconv2_mfma(
        const unsigned short* __restrict__ X,
        const unsigned short* __restrict__ Wk,
        float* __restrict__ out, int Cin, int Cout, int Hin) {
    constexpr int ROWS = NWN * TH + 1;
    constexpr int NPIX = ROWS * (W + 1);
    __shared__ unsigned short sB[NPIX * 40];
    const int tid = threadIdx.x;
    const int lane = tid & 63, wv = tid >> 6;
    const int wm = wv / NWN, wn = wv % NWN;
    const int n = lane & 31, kg = lane >> 5;
    const int y0 = blockIdx.x * (NWN * TH);
    const int coB = (blockIdx.y * NWM + wm) * 64;
    const int b = blockIdx.z;
    const int Yl = wn * TH + (n >> LW);
    const int Xl = n & (W - 1);
    v16f zero = {};
    v16f acc[2][2][2];
#pragma unroll
    for (int i = 0; i < 2; i++)
#pragma unroll
        for (int j = 0; j < 2; j++)
#pragma unroll
            for (int s = 0; s < 2; s++) acc[i][j][s] = zero;
    const unsigned short* Xb = X + (size_t)b * Hin * W * Cin;
    // fragment-ordered weight addressing
    const size_t cbStride = (size_t)(Cin >> 4) << 9;
    const size_t tStride  = (size_t)(Cout >> 5) * cbStride;
    const unsigned short* Af = Wk + (size_t)(coB >> 5) * cbStride + (lane << 3);
    const int PY[3] = {1, 0, 1}, DY[3] = {1, 0, 0};

    for (int ci0 = 0; ci0 < Cin; ci0 += 32) {
        for (int i = tid; i < NPIX * 4; i += 256) {
            int pix = i >> 2, part = i & 3;
            int py_ = pix / (W + 1), px_ = pix - py_ * (W + 1);
            int gy = y0 + py_, gx = px_;
            uint4 v = make_uint4(0u, 0u, 0u, 0u);
            if (gy < Hin && gx < W)
                v = *(const uint4*)(Xb + ((size_t)(gy * W + gx)) * Cin + ci0 + part * 8);
            *(uint4*)(sB + pix * 40 + part * 8) = v;
        }
        __syncthreads();
#pragma unroll
        for (int ky = 0; ky < 3; ky++) {
#pragma unroll
            for (int kx = 0; kx < 3; kx++) {
                const int py = PY[ky], dy = DY[ky];
                const int px = PY[kx], dx = DY[kx];
                const int t = ky * 3 + kx;
                const int boff = ((Yl + dy) * (W + 1) + (Xl + dx)) * 40 + kg * 8;
#pragma unroll
                for (int kh = 0; kh < 2; kh++) {
                    const unsigned short* ap =
                        Af + (size_t)t * tStride + (size_t)(((ci0 >> 4) + kh) << 9);
                    v8s B  = *(const v8s*)(sB + boff + kh * 16);
                    v8s A0 = *(const v8s*)(ap);
                    v8s A1 = *(const v8s*)(ap + cbStride);
                    acc[py][px][0] = __builtin_amdgcn_mfma_f32_32x32x16_bf16(A0, B, acc[py][px][0], 0, 0, 0);
                    acc[py][px][1] = __builtin_amdgcn_mfma_f32_32x32x16_bf16(A1, B, acc[py][px][1], 0, 0, 0);
                }
            }
        }
        __syncthreads();
    }
    // epilogue: parity pair (px=0,1) -> consecutive ox -> float2 store
    const int Wo = 2 * W, Ho = 2 * Hin;
    const int yin = y0 + Yl;
#pragma unroll
    for (int py = 0; py < 2; py++) {
        const int oy = 2 * yin + py;
#pragma unroll
        for (int sm = 0; sm < 2; sm++) {
            const int cobase = coB + sm * 32 + 4 * kg;
#pragma unroll
            for (int r = 0; r < 16; r++) {
                int co = cobase + (r & 3) + 8 * (r >> 2);
                float v0 = acc[py][0][sm][r]; v0 = v0 > 0.f ? v0 : 0.f;
                float v1 = acc[py][1][sm][r]; v1 = v1 > 0.f ? v1 : 0.f;
                *(float2*)(out + (((size_t)(b * Cout + co) * Ho + oy) * Wo + 2 * Xl)) =
                    make_float2(v0, v1);
            }
        }
    }
}

// =====================================================================
// Final stride-1 conv: Cout=3, tanh epilogue, fp32
// =====================================================================
__global__ __launch_bounds__(256) void conv_s1_c3_tanh_kernel(
        const float* __restrict__ in, const float* __restrict__ w,
        float* __restrict__ out, int Cin, int H, int W) {
    __shared__ float sIn[8][18][19];
    __shared__ float sW[8][3][9];
    const int tid = threadIdx.x;
    const int r = tid >> 4, c = tid & 15;
    const int ntx = W >> 4;
    const int tx0 = (blockIdx.x % ntx) << 4, ty0 = (blockIdx.x / ntx) << 4;
    const int b = blockIdx.z;
    const int hw = H * W;
    float acc[3] = {0.f, 0.f, 0.f};
    for (int ci0 = 0; ci0 < Cin; ci0 += 8) {
        for (int i = tid; i < 8 * 18 * 18; i += 256) {
            int ci = i / 324, rr = i % 324, ly = rr / 18, lx = rr % 18;
            int gy = ty0 + ly - 1, gx = tx0 + lx - 1;
            float v = 0.f;
            if (gy >= 0 && gy < H && gx >= 0 && gx < W)
                v = in[(size_t)(b * Cin + ci0 + ci) * hw + gy * W + gx];
            sIn[ci][ly][lx] = v;
        }
        for (int i = tid; i < 8 * 3 * 9; i += 256) {
            int ci = i / 27, rr = i % 27, co = rr / 9, k = rr % 9;
            sW[ci][co][k] = w[(size_t)((ci0 + ci) * 3 + co) * 9 + (8 - k)];
        }
        __syncthreads();
#pragma unroll
        for (int ci = 0; ci < 8; ci++) {
            float v00 = sIn[ci][r][c],     v01 = sIn[ci][r][c + 1],     v02 = sIn[ci][r][c + 2];
            float v10 = sIn[ci][r + 1][c], v11 = sIn[ci][r + 1][c + 1], v12 = sIn[ci][r + 1][c + 2];
            float v20 = sIn[ci][r + 2][c], v21 = sIn[ci][r + 2][c + 1], v22 = sIn[ci][r + 2][c + 2];
#pragma unroll
            for (int co = 0; co < 3; co++) {
                const float* wp = &sW[ci][co][0];
                acc[co] += v00 * wp[0] + v01 * wp[1] + v02 * wp[2]
                         + v10 * wp[3] + v11 * wp[4] + v12 * wp[5]
                         + v20 * wp[6] + v21 * wp[7] + v22 * wp[8];
            }
        }
        __syncthreads();
    }
#pragma unroll
    for (int co = 0; co < 3; co++)
        out[(size_t)(b * 3 + co) * hw + (ty0 + r) * W + tx0 + c] = tanhf(acc[co]);
}

// =====================================================================
// Host pipeline. d_out: out | feat_8 | feat_16 | feat_32.
// ws phase1 (bytes): A0/t16/t32 [0,67.1M) ; X8 [67.1M,68.2M) ;
//   Wk1 [68.2M,68.75M) ; X16 [0,33.5M) ; h1b [67.1M,83.9M) ;
//   Wk3 [83.9M,84.5M) ; Wk2 [84.5M,86.8M)
// ws phase2: Wk4 [0,0.3M) ; Wk5 [0.3M,0.45M) ; X32q [0.5M,8.9M) ;
//   h2b [8.9M,17.3M) ; h3q [17.3M,50.9M) ; tq [50.9M,52.4M)
// =====================================================================
extern "C" void kernel_launch(void* const* d_in, const int* in_sizes, int n_in,
                              void* d_out, int out_size, void* d_ws, size_t ws_size,
                              hipStream_t stream) {
    const float* cont = (const float*)d_in[0];
    const float* kv0 = (const float*)d_in[1];
    const float* kh0 = (const float*)d_in[2];
    const float* m0  = (const float*)d_in[3];
    const float* kv1 = (const float*)d_in[4];
    const float* kh1 = (const float*)d_in[5];
    const float* m1  = (const float*)d_in[6];
    const float* kv2 = (const float*)d_in[7];
    const float* kh2 = (const float*)d_in[8];
    const float* m2  = (const float*)d_in[9];
    const float* kv3 = (const float*)d_in[10];
    const float* kh3 = (const float*)d_in[11];
    const float* m3  = (const float*)d_in[12];
    const float* w1  = (const float*)d_in[13];
    const float* w2  = (const float*)d_in[14];
    const float* w3  = (const float*)d_in[15];
    const float* w4  = (const float*)d_in[16];
    const float* w5  = (const float*)d_in[17];
    const float* w6  = (const float*)d_in[18];

    float* out = (float*)d_out;
    float* f8  = out + 1572864;
    float* f16 = out + 2097152;
    float* f32 = out + 18874368;

    char* ws = (char*)d_ws;

    // ---- phase 1 ----
    float* A0 = (float*)ws;                                    // t16 fp32
    unsigned short* X8  = (unsigned short*)(ws + 67108864);
    unsigned short* Wk1 = (unsigned short*)(ws + 68157440);

    fusion_kernel<<<2048, 256, 0, stream>>>(cont, kv0, kh0, m0, f8, 64, 8, 8, 524288);
    nchw_to_nhwc_bf16<<<dim3(8, 128), 256, 8 * 72 * 2, stream>>>(f8, X8, 64, 8, 8, 3, 5);
    repack_w_frag<<<128, 256, 0, stream>>>(w1, Wk1, 64, 512, 0);
    deconv2_mfma<8, 4, 2, 2, 3><<<dim3(1, 4, 128), 256, 0, stream>>>(
        X8, Wk1, A0, 64, 512, 8);
    fusion_kernel<<<65536, 256, 0, stream>>>(A0, kv1, kh1, m1, f16, 512, 16, 16, 16777216);

    unsigned short* X16 = (unsigned short*)ws;
    unsigned short* h1b = (unsigned short*)(ws + 67108864);
    unsigned short* Wk3 = (unsigned short*)(ws + 83886080);
    unsigned short* Wk2 = (unsigned short*)(ws + 84475904);
    nchw_to_nhwc_bf16<<<dim3(16, 128), 256, 16 * 520 * 2, stream>>>(
        f16, X16, 512, 16, 16, 4, 8);
    repack_w_frag<<<512, 256, 0, stream>>>(w2, Wk2, 512, 256, 1);
    conv3x3_mfma<16, 8, 4><<<dim3(2, 2, 128), 256, 0, stream>>>(
        X16, Wk2, h1b, 512, 256, 16);
    repack_w_frag<<<128, 256, 0, stream>>>(w3, Wk3, 256, 128, 0);
    float* t32 = (float*)ws;
    deconv2_mfma<16, 2, 2, 2, 4><<<dim3(4, 1, 128), 256, 0, stream>>>(
        h1b, Wk3, t32, 256, 128, 16);
    fusion_kernel<<<65536, 256, 0, stream>>>(t32, kv2, kh2, m2, f32, 128, 32, 32, 16777216);

    // ---- phase 2: batch quarters ----
    unsigned short* Wk4  = (unsigned short*)ws;
    unsigned short* Wk5  = (unsigned short*)(ws + 294912);
    unsigned short* X32q = (unsigned short*)(ws + 524288);
    unsigned short* h2b  = (unsigned short*)(ws + 8912896);
    float* h3q = (float*)(ws + 17301504);
    float* tq  = (float*)(ws + 50855936);
    repack_w_frag<<<64, 256, 0, stream>>>(w4, Wk4, 128, 128, 1);
    repack_w_frag<<<32, 256, 0, stream>>>(w5, Wk5, 128, 64, 0);
    for (int q = 0; q < 4; q++) {
        size_t bo = (size_t)q * 32;
        const float* f32q = f32 + bo * 128 * 1024;
        nchw_to_nhwc_bf16<<<dim3(32, 32), 256, 32 * 136 * 2, stream>>>(
            f32q, X32q, 128, 32, 32, 5, 6);
        conv3x3_mfma<32, 4, 5><<<dim3(8, 1, 32), 256, 0, stream>>>(
            X32q, Wk4, h2b, 128, 128, 32);
        deconv2_mfma<32, 1, 4, 1, 5><<<dim3(8, 1, 32), 256, 0, stream>>>(
            h2b, Wk5, h3q, 128, 64, 32);
        conv_s1_c3_tanh_kernel<<<dim3(16, 1, 32), 256, 0, stream>>>(h3q, w6, tq, 64, 64, 64);
        fusion_kernel<<<1536, 256, 0, stream>>>(
            tq, kv3 + bo * 5 * 4096, kh3 + bo * 5 * 4096, m3 + bo * 4096,
            out + bo * 3 * 4096, 3, 64, 64, 393216);
    }
}

// Round 3
// 1058.806 us; speedup vs baseline: 1.1283x; 1.0492x over previous
//
#include <hip/hip_runtime.h>
#include <math.h>

typedef short v8s __attribute__((ext_vector_type(8)));
typedef float v16f __attribute__((ext_vector_type(16)));

// fp32 -> bf16 (RNE)
__device__ inline unsigned short f2bf(float f) {
    union { float f; unsigned u; } c; c.f = f;
    unsigned r = (c.u + 0x7fffu + ((c.u >> 16) & 1u)) >> 16;
    return (unsigned short)r;
}

// =====================================================================
// fusion v2: out = m * sepconv5(feat, kv, kh) + (1-m) * feat   (fp32)
// One thread per (b,pixel), looping CH channels: all pixel-side work
// (clamps, kv/kh/m loads, tap addressing) amortized over CH.
// Horizontal taps via ds_bpermute: lanes are consecutive x within a
// row group (W | 64), x-clamp folded into the bpermute index.
// Vertical clamp folded into the row load address. Identical
// accumulation order to the reference (h per row, then * kv).
// =====================================================================
template<int LW>
__global__ __launch_bounds__(256) void fusion2_kernel(
        const float* __restrict__ feat, const float* __restrict__ kv,
        const float* __restrict__ kh, const float* __restrict__ m,
        float* __restrict__ out, int C, int CH, int H, int lhw) {
    constexpr int W = 1 << LW;
    const int t = blockIdx.x * 256 + threadIdx.x;
    const int hw = H << LW;
    const int b = t >> lhw;
    const int pix = t & (hw - 1);
    const int x = pix & (W - 1);
    const int y = pix >> LW;
    const int lane = threadIdx.x & 63;
    const int rowbase = (lane & ~(W - 1)) << 2;   // byte base of row group

    const int c0 = blockIdx.y * CH;

    // per-pixel operands (channel-independent)
    const float mv = m[(size_t)b * hw + pix];
    float kvv[5], khv[5];
#pragma unroll
    for (int i = 0; i < 5; i++) {
        kvv[i] = kv[((size_t)b * 5 + i) * hw + pix];
        khv[i] = kh[((size_t)b * 5 + i) * hw + pix];
    }
    int idx[5];    // bpermute byte index for horizontal taps (x-clamped)
#pragma unroll
    for (int j = 0; j < 5; j++) {
        int xx = x + j - 2; xx = xx < 0 ? 0 : (xx >= W ? W - 1 : xx);
        idx[j] = rowbase + (xx << 2);
    }
    int roff[5];   // row load offset (y-clamped), at this lane's own x
#pragma unroll
    for (int i = 0; i < 5; i++) {
        int yy = y + i - 2; yy = yy < 0 ? 0 : (yy >= H ? H - 1 : yy);
        roff[i] = (yy << LW) + x;
    }

    const float* fbase = feat + ((size_t)b * C + c0) * hw;
    float* obase = out + ((size_t)b * C + c0) * hw + pix;
    const float om = 1.f - mv;

#pragma unroll 4
    for (int cc = 0; cc < CH; cc++) {
        const float* q = fbase + (size_t)cc * hw;
        float s = 0.f;
        float fv = 0.f;
#pragma unroll
        for (int i = 0; i < 5; i++) {
            float v = q[roff[i]];
            if (i == 2) fv = v;       // roff[2] == y*W+x (center, unclamped)
            int vb = __float_as_int(v);
            float h = 0.f;
#pragma unroll
            for (int j = 0; j < 5; j++) {
                float nv = __int_as_float(
                    __builtin_amdgcn_ds_bpermute(idx[j], vb));
                h += nv * khv[j];
            }
            s += kvv[i] * h;
        }
        obase[(size_t)cc * hw] = mv * s + om * fv;
    }
}

// =====================================================================
// NCHW fp32 -> NHWC bf16 transpose. One block per (y, b).
// =====================================================================
__global__ __launch_bounds__(256) void nchw_to_nhwc_bf16(
        const float* __restrict__ in, unsigned short* __restrict__ out,
        int C, int H, int W, int lw, int lc2) {
    extern __shared__ unsigned short sm_t[];
    const int y = blockIdx.x, b = blockIdx.y;
    const int Cp = C + 8;
    const int tid = threadIdx.x;
    for (int i = tid; i < C * W; i += 256) {
        int x = i & (W - 1), c = i >> lw;
        float v = in[(((size_t)b * C + c) * H + y) * W + x];
        sm_t[x * Cp + c] = f2bf(v);
    }
    __syncthreads();
    const unsigned* s32 = (const unsigned*)sm_t;
    unsigned* o32 = (unsigned*)(out + (((size_t)b * H + y) * W) * C);
    const int n32 = (W * C) >> 1;
    for (int i = tid; i < n32; i += 256) {
        int x = i >> lc2;
        int c2 = i - (x << lc2);
        o32[i] = s32[x * (Cp >> 1) + c2];
    }
}

// =====================================================================
// Repack [Cin][Cout][3][3] fp32 -> MFMA-fragment-ordered bf16:
//   [t][co>>5][ci>>4][ (kg=((ci>>3)&1))*32 + (co&31) ][ci&7]
// i.e. per (tap, 32-co block, 16-ci block): 512 contiguous shorts laid
// out so that lane = kg*32+n reads its v8s at base + lane*16B --
// a single fully-coalesced 1KiB load per wave (was a 64-line gather).
// flip=1: tap t stores source index 8-t (deconv-as-conv, stride 1).
// =====================================================================
__global__ __launch_bounds__(256) void repack_w_frag(
        const float* __restrict__ w, unsigned short* __restrict__ wk,
        int Cin, int Cout, int flip) {
    int idx = blockIdx.x * 256 + threadIdx.x;
    if (idx >= Cin * Cout) return;
    int ci = idx / Cout, co = idx - ci * Cout;
    const float* src = w + (size_t)idx * 9;
    const int nCb = Cout >> 5, nH = Cin >> 4;
    const size_t inner = (size_t)((((ci >> 3) & 1) * 32 + (co & 31)) * 8 + (ci & 7));
#pragma unroll
    for (int k = 0; k < 9; k++) {
        int t = flip ? (8 - k) : k;
        size_t blk = ((size_t)t * nCb + (co >> 5)) * nH + (ci >> 4);
        wk[(blk << 9) + inner] = f2bf(src[k]);
    }
}

// =====================================================================
// 3x3 conv (pad 1, pre-flipped weights) MFMA implicit GEMM + ReLU.
// X: [B,H,W,Cin] bf16. Wk: fragment-ordered bf16 (repack_w_frag).
// out: [B,H,W,Cout] bf16.
// Block = 4 waves (2x2); tile M=128 co x N=128 px. Wave 64x64.
// =====================================================================
template<int W, int TH, int LW>
__global__ __launch_bounds__(256) void conv3x3_mfma(
        const unsigned short* __restrict__ X,
        const unsigned short* __restrict__ Wk,
        unsigned short* __restrict__ out, int Cin, int Cout, int H) {
    constexpr int TP = (TH + 2) * (W + 2);
    __shared__ unsigned short sB[TP * 40];
    const int tid = threadIdx.x;
    const int lane = tid & 63, wv = tid >> 6;
    const int wm = wv >> 1, wn = wv & 1;
    const int y0 = blockIdx.x * TH;
    const int coB = blockIdx.y * 128 + wm * 64;
    const int b = blockIdx.z;
    const int n = lane & 31, kg = lane >> 5;
    const int p0 = wn * 64 + n, p1 = p0 + 32;
    const int r0 = p0 >> LW, c0 = p0 & (W - 1);
    const int r1 = p1 >> LW, c1 = p1 & (W - 1);
    const int bo0 = (r0 * (W + 2) + c0) * 40 + kg * 8;
    const int bo1 = (r1 * (W + 2) + c1) * 40 + kg * 8;
    v16f acc00 = {}, acc01 = {}, acc10 = {}, acc11 = {};
    // fragment-ordered weight addressing
    const size_t cbStride = (size_t)(Cin >> 4) << 9;          // shorts per 32-co block
    const size_t tStride  = (size_t)(Cout >> 5) * cbStride;   // shorts per tap
    const unsigned short* Af = Wk + (size_t)(coB >> 5) * cbStride + (lane << 3);
    const unsigned short* Xb = X + (size_t)b * H * W * Cin;

    for (int ci0 = 0; ci0 < Cin; ci0 += 32) {
        for (int i = tid; i < TP * 4; i += 256) {
            int pix = i >> 2, part = i & 3;
            int py = pix / (W + 2), px = pix - py * (W + 2);
            int gy = y0 + py - 1, gx = px - 1;
            uint4 v = make_uint4(0u, 0u, 0u, 0u);
            if (gy >= 0 && gy < H && (unsigned)gx < (unsigned)W)
                v = *(const uint4*)(Xb + ((size_t)(gy * W + gx)) * Cin + ci0 + part * 8);
            *(uint4*)(sB + pix * 40 + part * 8) = v;
        }
        __syncthreads();
#pragma unroll
        for (int t = 0; t < 9; t++) {
            const int ky = t / 3, kx = t - ky * 3;
            const int toff = (ky * (W + 2) + kx) * 40;
#pragma unroll
            for (int kh = 0; kh < 2; kh++) {
                const unsigned short* ap =
                    Af + (size_t)t * tStride + (size_t)(((ci0 >> 4) + kh) << 9);
                v8s A0 = *(const v8s*)(ap);
                v8s A1 = *(const v8s*)(ap + cbStride);
                v8s B0 = *(const v8s*)(sB + bo0 + toff + kh * 16);
                v8s B1 = *(const v8s*)(sB + bo1 + toff + kh * 16);
                acc00 = __builtin_amdgcn_mfma_f32_32x32x16_bf16(A0, B0, acc00, 0, 0, 0);
                acc01 = __builtin_amdgcn_mfma_f32_32x32x16_bf16(A0, B1, acc01, 0, 0, 0);
                acc10 = __builtin_amdgcn_mfma_f32_32x32x16_bf16(A1, B0, acc10, 0, 0, 0);
                acc11 = __builtin_amdgcn_mfma_f32_32x32x16_bf16(A1, B1, acc11, 0, 0, 0);
            }
        }
        __syncthreads();
    }
    // C/D: col=lane&31 -> pixel, row r -> co = base + (r&3) + 8*(r>>2) + 4*kg
    unsigned short* ob = out + (size_t)b * H * W * Cout;
#pragma unroll
    for (int sm = 0; sm < 2; sm++) {
        v16f a0 = sm ? acc10 : acc00;
        v16f a1 = sm ? acc11 : acc01;
        const int cobase = coB + sm * 32 + 4 * kg;
        unsigned short* q0p = ob + ((size_t)((y0 + r0) * W + c0)) * Cout + cobase;
        unsigned short* q1p = ob + ((size_t)((y0 + r1) * W + c1)) * Cout + cobase;
#pragma unroll
        for (int r2 = 0; r2 < 4; r2++) {
            ushort4 q0, q1; float v;
            v = a0[4 * r2 + 0]; v = v > 0.f ? v : 0.f; q0.x = f2bf(v);
            v = a0[4 * r2 + 1]; v = v > 0.f ? v : 0.f; q0.y = f2bf(v);
            v = a0[4 * r2 + 2]; v = v > 0.f ? v : 0.f; q0.z = f2bf(v);
            v = a0[4 * r2 + 3]; v = v > 0.f ? v : 0.f; q0.w = f2bf(v);
            *(ushort4*)(q0p + 8 * r2) = q0;
            v = a1[4 * r2 + 0]; v = v > 0.f ? v : 0.f; q1.x = f2bf(v);
            v = a1[4 * r2 + 1]; v = v > 0.f ? v : 0.f; q1.y = f2bf(v);
            v = a1[4 * r2 + 2]; v = v > 0.f ? v : 0.f; q1.z = f2bf(v);
            v = a1[4 * r2 + 3]; v = v > 0.f ? v : 0.f; q1.w = f2bf(v);
            *(ushort4*)(q1p + 8 * r2) = q1;
        }
    }
}

// =====================================================================
// stride-2 deconv (k=3,p=1,op=1) as 4 parity convs on MFMA + ReLU.
// out(2Y+py, 2X+px): ky set = {1} if py==0 else {2 (dy=0), 0 (dy=1)}.
// X: [B,Hin,W,Cin] NHWC bf16. Wk: fragment-ordered bf16 UNflipped.
// out: [B,Cout,2Hin,2W] fp32 NCHW. Block = NWM*NWN waves; wave:
// M=64 co, N=32 px strip (TH rows x W), 4 parities (8 v16f accs).
// =====================================================================
template<int W, int TH, int NWN, int NWM, int LW>
__global__ __launch_bounds__(256) void deconv2_mfma(
        const unsigned short* __restrict__ X,
        const unsigned short* __restrict__ Wk,
        float* __restrict__ out, int Cin, int Cout, int Hin) {
    constexpr int ROWS = NWN * TH + 1;
    constexpr int NPIX = ROWS * (W + 1);
    __shared__ unsigned short sB[NPIX * 40];
    const int tid = threadIdx.x;
    const int lane = tid & 63, wv = tid >> 6;
    const int wm = wv / NWN, wn = wv % NWN;
    const int n = lane & 31, kg = lane >> 5;
    const int y0 = blockIdx.x * (NWN * TH);
    const int coB = (blockIdx.y * NWM + wm) * 64;
    const int b = blockIdx.z;
    const int Yl = wn * TH + (n >> LW);
    const int Xl = n & (W - 1);
    v16f zero = {};
    v16f acc[2][2][2];
#pragma unroll
    for (int i = 0; i < 2; i++)
#pragma unroll
        for (int j = 0; j < 2; j++)
#pragma unroll
            for (int s = 0; s < 2; s++) acc[i][j][s] = zero;
    const unsigned short* Xb = X + (size_t)b * Hin * W * Cin;
    // fragment-ordered weight addressing
    const size_t cbStride = (size_t)(Cin >> 4) << 9;
    const size_t tStride  = (size_t)(Cout >> 5) * cbStride;
    const unsigned short* Af = Wk + (size_t)(coB >> 5) * cbStride + (lane << 3);
    const int PY[3] = {1, 0, 1}, DY[3] = {1, 0, 0};

    for (int ci0 = 0; ci0 < Cin; ci0 += 32) {
        for (int i = tid; i < NPIX * 4; i += 256) {
            int pix = i >> 2, part = i & 3;
            int py_ = pix / (W + 1), px_ = pix - py_ * (W + 1);
            int gy = y0 + py_, gx = px_;
            uint4 v = make_uint4(0u, 0u, 0u, 0u);
            if (gy < Hin && gx < W)
                v = *(const uint4*)(Xb + ((size_t)(gy * W + gx)) * Cin + ci0 + part * 8);
            *(uint4*)(sB + pix * 40 + part * 8) = v;
        }
        __syncthreads();
#pragma unroll
        for (int ky = 0; ky < 3; ky++) {
#pragma unroll
            for (int kx = 0; kx < 3; kx++) {
                const int py = PY[ky], dy = DY[ky];
                const int px = PY[kx], dx = DY[kx];
                const int t = ky * 3 + kx;
                const int boff = ((Yl + dy) * (W + 1) + (Xl + dx)) * 40 + kg * 8;
#pragma unroll
                for (int kh = 0; kh < 2; kh++) {
                    const unsigned short* ap =
                        Af + (size_t)t * tStride + (size_t)(((ci0 >> 4) + kh) << 9);
                    v8s B  = *(const v8s*)(sB + boff + kh * 16);
                    v8s A0 = *(const v8s*)(ap);
                    v8s A1 = *(const v8s*)(ap + cbStride);
                    acc[py][px][0] = __builtin_amdgcn_mfma_f32_32x32x16_bf16(A0, B, acc[py][px][0], 0, 0, 0);
                    acc[py][px][1] = __builtin_amdgcn_mfma_f32_32x32x16_bf16(A1, B, acc[py][px][1], 0, 0, 0);
                }
            }
        }
        __syncthreads();
    }
    // epilogue: parity pair (px=0,1) -> consecutive ox -> float2 store
    const int Wo = 2 * W, Ho = 2 * Hin;
    const int yin = y0 + Yl;
#pragma unroll
    for (int py = 0; py < 2; py++) {
        const int oy = 2 * yin + py;
#pragma unroll
        for (int sm = 0; sm < 2; sm++) {
            const int cobase = coB + sm * 32 + 4 * kg;
#pragma unroll
            for (int r = 0; r < 16; r++) {
                int co = cobase + (r & 3) + 8 * (r >> 2);
                float v0 = acc[py][0][sm][r]; v0 = v0 > 0.f ? v0 : 0.f;
                float v1 = acc[py][1][sm][r]; v1 = v1 > 0.f ? v1 : 0.f;
                *(float2*)(out + (((size_t)(b * Cout + co) * Ho + oy) * Wo + 2 * Xl)) =
                    make_float2(v0, v1);
            }
        }
    }
}

// =====================================================================
// Final stride-1 conv: Cout=3, tanh epilogue, fp32
// =====================================================================
__global__ __launch_bounds__(256) void conv_s1_c3_tanh_kernel(
        const float* __restrict__ in, const float* __restrict__ w,
        float* __restrict__ out, int Cin, int H, int W) {
    __shared__ float sIn[8][18][19];
    __shared__ float sW[8][3][9];
    const int tid = threadIdx.x;
    const int r = tid >> 4, c = tid & 15;
    const int ntx = W >> 4;
    const int tx0 = (blockIdx.x % ntx) << 4, ty0 = (blockIdx.x / ntx) << 4;
    const int b = blockIdx.z;
    const int hw = H * W;
    float acc[3] = {0.f, 0.f, 0.f};
    for (int ci0 = 0; ci0 < Cin; ci0 += 8) {
        for (int i = tid; i < 8 * 18 * 18; i += 256) {
            int ci = i / 324, rr = i % 324, ly = rr / 18, lx = rr % 18;
            int gy = ty0 + ly - 1, gx = tx0 + lx - 1;
            float v = 0.f;
            if (gy >= 0 && gy < H && gx >= 0 && gx < W)
                v = in[(size_t)(b * Cin + ci0 + ci) * hw + gy * W + gx];
            sIn[ci][ly][lx] = v;
        }
        for (int i = tid; i < 8 * 3 * 9; i += 256) {
            int ci = i / 27, rr = i % 27, co = rr / 9, k = rr % 9;
            sW[ci][co][k] = w[(size_t)((ci0 + ci) * 3 + co) * 9 + (8 - k)];
        }
        __syncthreads();
#pragma unroll
        for (int ci = 0; ci < 8; ci++) {
            float v00 = sIn[ci][r][c],     v01 = sIn[ci][r][c + 1],     v02 = sIn[ci][r][c + 2];
            float v10 = sIn[ci][r + 1][c], v11 = sIn[ci][r + 1][c + 1], v12 = sIn[ci][r + 1][c + 2];
            float v20 = sIn[ci][r + 2][c], v21 = sIn[ci][r + 2][c + 1], v22 = sIn[ci][r + 2][c + 2];
#pragma unroll
            for (int co = 0; co < 3; co++) {
                const float* wp = &sW[ci][co][0];
                acc[co] += v00 * wp[0] + v01 * wp[1] + v02 * wp[2]
                         + v10 * wp[3] + v11 * wp[4] + v12 * wp[5]
                         + v20 * wp[6] + v21 * wp[7] + v22 * wp[8];
            }
        }
        __syncthreads();
    }
#pragma unroll
    for (int co = 0; co < 3; co++)
        out[(size_t)(b * 3 + co) * hw + (ty0 + r) * W + tx0 + c] = tanhf(acc[co]);
}

// =====================================================================
// Host pipeline. d_out: out | feat_8 | feat_16 | feat_32.
// ws phase1 (bytes): A0/t16/t32 [0,67.1M) ; X8 [67.1M,68.2M) ;
//   Wk1 [68.2M,68.75M) ; X16 [0,33.5M) ; h1b [67.1M,83.9M) ;
//   Wk3 [83.9M,84.5M) ; Wk2 [84.5M,86.8M)
// ws phase2: Wk4 [0,0.3M) ; Wk5 [0.3M,0.45M) ; X32q [0.5M,8.9M) ;
//   h2b [8.9M,17.3M) ; h3q [17.3M,50.9M) ; tq [50.9M,52.4M)
// =====================================================================
extern "C" void kernel_launch(void* const* d_in, const int* in_sizes, int n_in,
                              void* d_out, int out_size, void* d_ws, size_t ws_size,
                              hipStream_t stream) {
    const float* cont = (const float*)d_in[0];
    const float* kv0 = (const float*)d_in[1];
    const float* kh0 = (const float*)d_in[2];
    const float* m0  = (const float*)d_in[3];
    const float* kv1 = (const float*)d_in[4];
    const float* kh1 = (const float*)d_in[5];
    const float* m1  = (const float*)d_in[6];
    const float* kv2 = (const float*)d_in[7];
    const float* kh2 = (const float*)d_in[8];
    const float* m2  = (const float*)d_in[9];
    const float* kv3 = (const float*)d_in[10];
    const float* kh3 = (const float*)d_in[11];
    const float* m3  = (const float*)d_in[12];
    const float* w1  = (const float*)d_in[13];
    const float* w2  = (const float*)d_in[14];
    const float* w3  = (const float*)d_in[15];
    const float* w4  = (const float*)d_in[16];
    const float* w5  = (const float*)d_in[17];
    const float* w6  = (const float*)d_in[18];

    float* out = (float*)d_out;
    float* f8  = out + 1572864;
    float* f16 = out + 2097152;
    float* f32 = out + 18874368;

    char* ws = (char*)d_ws;

    // ---- phase 1 ----
    float* A0 = (float*)ws;                                    // t16 fp32
    unsigned short* X8  = (unsigned short*)(ws + 67108864);
    unsigned short* Wk1 = (unsigned short*)(ws + 68157440);

    // f8 fusion: C=64, 8x8 (LW=3), hw=64 (lhw=6), CH=16
    fusion2_kernel<3><<<dim3(32, 4), 256, 0, stream>>>(
        cont, kv0, kh0, m0, f8, 64, 16, 8, 6);
    nchw_to_nhwc_bf16<<<dim3(8, 128), 256, 8 * 72 * 2, stream>>>(f8, X8, 64, 8, 8, 3, 5);
    repack_w_frag<<<128, 256, 0, stream>>>(w1, Wk1, 64, 512, 0);
    deconv2_mfma<8, 4, 2, 2, 3><<<dim3(1, 4, 128), 256, 0, stream>>>(
        X8, Wk1, A0, 64, 512, 8);
    // f16 fusion: C=512, 16x16 (LW=4), hw=256 (lhw=8), CH=16
    fusion2_kernel<4><<<dim3(128, 32), 256, 0, stream>>>(
        A0, kv1, kh1, m1, f16, 512, 16, 16, 8);

    unsigned short* X16 = (unsigned short*)ws;
    unsigned short* h1b = (unsigned short*)(ws + 67108864);
    unsigned short* Wk3 = (unsigned short*)(ws + 83886080);
    unsigned short* Wk2 = (unsigned short*)(ws + 84475904);
    nchw_to_nhwc_bf16<<<dim3(16, 128), 256, 16 * 520 * 2, stream>>>(
        f16, X16, 512, 16, 16, 4, 8);
    repack_w_frag<<<512, 256, 0, stream>>>(w2, Wk2, 512, 256, 1);
    conv3x3_mfma<16, 8, 4><<<dim3(2, 2, 128), 256, 0, stream>>>(
        X16, Wk2, h1b, 512, 256, 16);
    repack_w_frag<<<128, 256, 0, stream>>>(w3, Wk3, 256, 128, 0);
    float* t32 = (float*)ws;
    deconv2_mfma<16, 2, 2, 2, 4><<<dim3(4, 1, 128), 256, 0, stream>>>(
        h1b, Wk3, t32, 256, 128, 16);
    // f32 fusion: C=128, 32x32 (LW=5), hw=1024 (lhw=10), CH=16
    fusion2_kernel<5><<<dim3(512, 8), 256, 0, stream>>>(
        t32, kv2, kh2, m2, f32, 128, 16, 32, 10);

    // ---- phase 2: batch quarters ----
    unsigned short* Wk4  = (unsigned short*)ws;
    unsigned short* Wk5  = (unsigned short*)(ws + 294912);
    unsigned short* X32q = (unsigned short*)(ws + 524288);
    unsigned short* h2b  = (unsigned short*)(ws + 8912896);
    float* h3q = (float*)(ws + 17301504);
    float* tq  = (float*)(ws + 50855936);
    repack_w_frag<<<64, 256, 0, stream>>>(w4, Wk4, 128, 128, 1);
    repack_w_frag<<<32, 256, 0, stream>>>(w5, Wk5, 128, 64, 0);
    for (int q = 0; q < 4; q++) {
        size_t bo = (size_t)q * 32;
        const float* f32q = f32 + bo * 128 * 1024;
        nchw_to_nhwc_bf16<<<dim3(32, 32), 256, 32 * 136 * 2, stream>>>(
            f32q, X32q, 128, 32, 32, 5, 6);
        conv3x3_mfma<32, 4, 5><<<dim3(8, 1, 32), 256, 0, stream>>>(
            X32q, Wk4, h2b, 128, 128, 32);
        deconv2_mfma<32, 1, 4, 1, 5><<<dim3(8, 1, 32), 256, 0, stream>>>(
            h2b, Wk5, h3q, 128, 64, 32);
        conv_s1_c3_tanh_kernel<<<dim3(16, 1, 32), 256, 0, stream>>>(h3q, w6, tq, 64, 64, 64);
        // out fusion: C=3, 64x64 (LW=6), hw=4096 (lhw=12), CH=3, B_q=32
        fusion2_kernel<6><<<dim3(512, 1), 256, 0, stream>>>(
            tq, kv3 + bo * 5 * 4096, kh3 + bo * 5 * 4096, m3 + bo * 4096,
            out + bo * 3 * 4096, 3, 3, 64, 12);
    }
}

// Round 4
// 1045.258 us; speedup vs baseline: 1.1429x; 1.0130x over previous
//
#include <hip/hip_runtime.h>
#include <math.h>

typedef short v8s __attribute__((ext_vector_type(8)));
typedef float v16f __attribute__((ext_vector_type(16)));

// fp32 -> bf16 (RNE)
__device__ inline unsigned short f2bf(float f) {
    union { float f; unsigned u; } c; c.f = f;
    unsigned r = (c.u + 0x7fffu + ((c.u >> 16) & 1u)) >> 16;
    return (unsigned short)r;
}

// =====================================================================
// fusion v2: out = m * sepconv5(feat, kv, kh) + (1-m) * feat   (fp32)
// One thread per (b,pixel), looping CH channels. Horizontal taps via
// ds_bpermute (x-clamp folded into index); vertical clamp in address.
// =====================================================================
template<int LW>
__global__ __launch_bounds__(256) void fusion2_kernel(
        const float* __restrict__ feat, const float* __restrict__ kv,
        const float* __restrict__ kh, const float* __restrict__ m,
        float* __restrict__ out, int C, int CH, int H, int lhw) {
    constexpr int W = 1 << LW;
    const int t = blockIdx.x * 256 + threadIdx.x;
    const int hw = H << LW;
    const int b = t >> lhw;
    const int pix = t & (hw - 1);
    const int x = pix & (W - 1);
    const int y = pix >> LW;
    const int lane = threadIdx.x & 63;
    const int rowbase = (lane & ~(W - 1)) << 2;   // byte base of row group

    const int c0 = blockIdx.y * CH;

    const float mv = m[(size_t)b * hw + pix];
    float kvv[5], khv[5];
#pragma unroll
    for (int i = 0; i < 5; i++) {
        kvv[i] = kv[((size_t)b * 5 + i) * hw + pix];
        khv[i] = kh[((size_t)b * 5 + i) * hw + pix];
    }
    int idx[5];
#pragma unroll
    for (int j = 0; j < 5; j++) {
        int xx = x + j - 2; xx = xx < 0 ? 0 : (xx >= W ? W - 1 : xx);
        idx[j] = rowbase + (xx << 2);
    }
    int roff[5];
#pragma unroll
    for (int i = 0; i < 5; i++) {
        int yy = y + i - 2; yy = yy < 0 ? 0 : (yy >= H ? H - 1 : yy);
        roff[i] = (yy << LW) + x;
    }

    const float* fbase = feat + ((size_t)b * C + c0) * hw;
    float* obase = out + ((size_t)b * C + c0) * hw + pix;
    const float om = 1.f - mv;

#pragma unroll 4
    for (int cc = 0; cc < CH; cc++) {
        const float* q = fbase + (size_t)cc * hw;
        float s = 0.f;
        float fv = 0.f;
#pragma unroll
        for (int i = 0; i < 5; i++) {
            float v = q[roff[i]];
            if (i == 2) fv = v;
            int vb = __float_as_int(v);
            float h = 0.f;
#pragma unroll
            for (int j = 0; j < 5; j++) {
                float nv = __int_as_float(
                    __builtin_amdgcn_ds_bpermute(idx[j], vb));
                h += nv * khv[j];
            }
            s += kvv[i] * h;
        }
        obase[(size_t)cc * hw] = mv * s + om * fv;
    }
}

// =====================================================================
// NCHW fp32 -> NHWC bf16 transpose. One block per (y, b).
// =====================================================================
__global__ __launch_bounds__(256) void nchw_to_nhwc_bf16(
        const float* __restrict__ in, unsigned short* __restrict__ out,
        int C, int H, int W, int lw, int lc2) {
    extern __shared__ unsigned short sm_t[];
    const int y = blockIdx.x, b = blockIdx.y;
    const int Cp = C + 8;
    const int tid = threadIdx.x;
    for (int i = tid; i < C * W; i += 256) {
        int x = i & (W - 1), c = i >> lw;
        float v = in[(((size_t)b * C + c) * H + y) * W + x];
        sm_t[x * Cp + c] = f2bf(v);
    }
    __syncthreads();
    const unsigned* s32 = (const unsigned*)sm_t;
    unsigned* o32 = (unsigned*)(out + (((size_t)b * H + y) * W) * C);
    const int n32 = (W * C) >> 1;
    for (int i = tid; i < n32; i += 256) {
        int x = i >> lc2;
        int c2 = i - (x << lc2);
        o32[i] = s32[x * (Cp >> 1) + c2];
    }
}

// =====================================================================
// Repack [Cin][Cout][3][3] fp32 -> MFMA-fragment-ordered bf16:
//   [t][co>>5][ci>>4][ (kg=((ci>>3)&1))*32 + (co&31) ][ci&7]
// Wave A-load = base + lane*16B, one coalesced 1KiB read.
// flip=1: tap t stores source index 8-t (deconv-as-conv, stride 1).
// =====================================================================
__global__ __launch_bounds__(256) void repack_w_frag(
        const float* __restrict__ w, unsigned short* __restrict__ wk,
        int Cin, int Cout, int flip) {
    int idx = blockIdx.x * 256 + threadIdx.x;
    if (idx >= Cin * Cout) return;
    int ci = idx / Cout, co = idx - ci * Cout;
    const float* src = w + (size_t)idx * 9;
    const int nCb = Cout >> 5, nH = Cin >> 4;
    const size_t inner = (size_t)((((ci >> 3) & 1) * 32 + (co & 31)) * 8 + (ci & 7));
#pragma unroll
    for (int k = 0; k < 9; k++) {
        int t = flip ? (8 - k) : k;
        size_t blk = ((size_t)t * nCb + (co >> 5)) * nH + (ci >> 4);
        wk[(blk << 9) + inner] = f2bf(src[k]);
    }
}

// =====================================================================
// 3x3 conv (pad 1, pre-flipped weights) MFMA implicit GEMM + ReLU.
// Double-buffered LDS with async-stage split: issue tile k+1 global
// loads into regs BEFORE MFMA on tile k; ds_write after; ONE barrier
// per K-iter. Global latency hides under the 72-MFMA cluster.
// =====================================================================
template<int W, int TH, int LW>
__global__ __launch_bounds__(256) void conv3x3_mfma(
        const unsigned short* __restrict__ X,
        const unsigned short* __restrict__ Wk,
        unsigned short* __restrict__ out, int Cin, int Cout, int H) {
    constexpr int TP = (TH + 2) * (W + 2);
    constexpr int NIT = TP * 4;
    constexpr int NLD = (NIT + 255) / 256;
    __shared__ unsigned short sB[2][TP * 40];
    const int tid = threadIdx.x;
    const int lane = tid & 63, wv = tid >> 6;
    const int wm = wv >> 1, wn = wv & 1;
    const int y0 = blockIdx.x * TH;
    const int coB = blockIdx.y * 128 + wm * 64;
    const int b = blockIdx.z;
    const int n = lane & 31, kg = lane >> 5;
    const int p0 = wn * 64 + n, p1 = p0 + 32;
    const int r0 = p0 >> LW, c0 = p0 & (W - 1);
    const int r1 = p1 >> LW, c1 = p1 & (W - 1);
    const int bo0 = (r0 * (W + 2) + c0) * 40 + kg * 8;
    const int bo1 = (r1 * (W + 2) + c1) * 40 + kg * 8;
    v16f acc00 = {}, acc01 = {}, acc10 = {}, acc11 = {};
    const size_t cbStride = (size_t)(Cin >> 4) << 9;          // shorts per 32-co block
    const size_t tStride  = (size_t)(Cout >> 5) * cbStride;   // shorts per tap
    const unsigned short* Af = Wk + (size_t)(coB >> 5) * cbStride + (lane << 3);
    const unsigned short* Xb = X + (size_t)b * H * W * Cin;

    // staging descriptors (K-invariant)
    const unsigned short* ldp[NLD];
    int sto[NLD];
#pragma unroll
    for (int s = 0; s < NLD; s++) {
        int i = tid + s * 256;
        bool slot = (i < NIT);
        int pix = i >> 2, part = i & 3;
        int py = pix / (W + 2), px = pix - py * (W + 2);
        int gy = y0 + py - 1, gx = px - 1;
        bool ok = slot && gy >= 0 && gy < H && (unsigned)gx < (unsigned)W;
        ldp[s] = ok ? Xb + ((size_t)(gy * W + gx)) * Cin + part * 8 : nullptr;
        sto[s] = slot ? pix * 40 + part * 8 : -1;
    }

    // prologue: stage tile 0 into buf 0
    uint4 pre[NLD];
#pragma unroll
    for (int s = 0; s < NLD; s++)
        pre[s] = ldp[s] ? *(const uint4*)(ldp[s]) : make_uint4(0u, 0u, 0u, 0u);
#pragma unroll
    for (int s = 0; s < NLD; s++)
        if (sto[s] >= 0) *(uint4*)(sB[0] + sto[s]) = pre[s];
    __syncthreads();

    const int NK = Cin >> 5;
    for (int kk = 0; kk < NK; kk++) {
        const int cur = kk & 1;
        const int ci0 = kk << 5;
        const bool more = (kk + 1 < NK);
        if (more) {
#pragma unroll
            for (int s = 0; s < NLD; s++)
                pre[s] = ldp[s] ? *(const uint4*)(ldp[s] + ci0 + 32)
                                : make_uint4(0u, 0u, 0u, 0u);
        }
        const unsigned short* sC = sB[cur];
#pragma unroll
        for (int t = 0; t < 9; t++) {
            const int ky = t / 3, kx = t - ky * 3;
            const int toff = (ky * (W + 2) + kx) * 40;
#pragma unroll
            for (int kh = 0; kh < 2; kh++) {
                const unsigned short* ap =
                    Af + (size_t)t * tStride + (size_t)(((ci0 >> 4) + kh) << 9);
                v8s A0 = *(const v8s*)(ap);
                v8s A1 = *(const v8s*)(ap + cbStride);
                v8s B0 = *(const v8s*)(sC + bo0 + toff + kh * 16);
                v8s B1 = *(const v8s*)(sC + bo1 + toff + kh * 16);
                acc00 = __builtin_amdgcn_mfma_f32_32x32x16_bf16(A0, B0, acc00, 0, 0, 0);
                acc01 = __builtin_amdgcn_mfma_f32_32x32x16_bf16(A0, B1, acc01, 0, 0, 0);
                acc10 = __builtin_amdgcn_mfma_f32_32x32x16_bf16(A1, B0, acc10, 0, 0, 0);
                acc11 = __builtin_amdgcn_mfma_f32_32x32x16_bf16(A1, B1, acc11, 0, 0, 0);
            }
        }
        if (more) {
            unsigned short* sN = sB[cur ^ 1];
#pragma unroll
            for (int s = 0; s < NLD; s++)
                if (sto[s] >= 0) *(uint4*)(sN + sto[s]) = pre[s];
            __syncthreads();
        }
    }
    // C/D: col=lane&31 -> pixel, row r -> co = base + (r&3) + 8*(r>>2) + 4*kg
    unsigned short* ob = out + (size_t)b * H * W * Cout;
#pragma unroll
    for (int sm = 0; sm < 2; sm++) {
        v16f a0 = sm ? acc10 : acc00;
        v16f a1 = sm ? acc11 : acc01;
        const int cobase = coB + sm * 32 + 4 * kg;
        unsigned short* q0p = ob + ((size_t)((y0 + r0) * W + c0)) * Cout + cobase;
        unsigned short* q1p = ob + ((size_t)((y0 + r1) * W + c1)) * Cout + cobase;
#pragma unroll
        for (int r2 = 0; r2 < 4; r2++) {
            ushort4 q0, q1; float v;
            v = a0[4 * r2 + 0]; v = v > 0.f ? v : 0.f; q0.x = f2bf(v);
            v = a0[4 * r2 + 1]; v = v > 0.f ? v : 0.f; q0.y = f2bf(v);
            v = a0[4 * r2 + 2]; v = v > 0.f ? v : 0.f; q0.z = f2bf(v);
            v = a0[4 * r2 + 3]; v = v > 0.f ? v : 0.f; q0.w = f2bf(v);
            *(ushort4*)(q0p + 8 * r2) = q0;
            v = a1[4 * r2 + 0]; v = v > 0.f ? v : 0.f; q1.x = f2bf(v);
            v = a1[4 * r2 + 1]; v = v > 0.f ? v : 0.f; q1.y = f2bf(v);
            v = a1[4 * r2 + 2]; v = v > 0.f ? v : 0.f; q1.z = f2bf(v);
            v = a1[4 * r2 + 3]; v = v > 0.f ? v : 0.f; q1.w = f2bf(v);
            *(ushort4*)(q1p + 8 * r2) = q1;
        }
    }
}

// =====================================================================
// stride-2 deconv (k=3,p=1,op=1) as 4 parity convs on MFMA + ReLU.
// Same double-buffered async-stage structure as conv3x3_mfma.
// =====================================================================
template<int W, int TH, int NWN, int NWM, int LW>
__global__ __launch_bounds__(256) void deconv2_mfma(
        const unsigned short* __restrict__ X,
        const unsigned short* __restrict__ Wk,
        float* __restrict__ out, int Cin, int Cout, int Hin) {
    constexpr int ROWS = NWN * TH + 1;
    constexpr int NPIX = ROWS * (W + 1);
    constexpr int NIT = NPIX * 4;
    constexpr int NLD = (NIT + 255) / 256;
    __shared__ unsigned short sB[2][NPIX * 40];
    const int tid = threadIdx.x;
    const int lane = tid & 63, wv = tid >> 6;
    const int wm = wv / NWN, wn = wv % NWN;
    const int n = lane & 31, kg = lane >> 5;
    const int y0 = blockIdx.x * (NWN * TH);
    const int coB = (blockIdx.y * NWM + wm) * 64;
    const int b = blockIdx.z;
    const int Yl = wn * TH + (n >> LW);
    const int Xl = n & (W - 1);
    v16f zero = {};
    v16f acc[2][2][2];
#pragma unroll
    for (int i = 0; i < 2; i++)
#pragma unroll
        for (int j = 0; j < 2; j++)
#pragma unroll
            for (int s = 0; s < 2; s++) acc[i][j][s] = zero;
    const unsigned short* Xb = X + (size_t)b * Hin * W * Cin;
    const size_t cbStride = (size_t)(Cin >> 4) << 9;
    const size_t tStride  = (size_t)(Cout >> 5) * cbStride;
    const unsigned short* Af = Wk + (size_t)(coB >> 5) * cbStride + (lane << 3);
    const int PY[3] = {1, 0, 1}, DY[3] = {1, 0, 0};

    // staging descriptors (K-invariant)
    const unsigned short* ldp[NLD];
    int sto[NLD];
#pragma unroll
    for (int s = 0; s < NLD; s++) {
        int i = tid + s * 256;
        bool slot = (i < NIT);
        int pix = i >> 2, part = i & 3;
        int py_ = pix / (W + 1), px_ = pix - py_ * (W + 1);
        int gy = y0 + py_, gx = px_;
        bool ok = slot && gy < Hin && gx < W;
        ldp[s] = ok ? Xb + ((size_t)(gy * W + gx)) * Cin + part * 8 : nullptr;
        sto[s] = slot ? pix * 40 + part * 8 : -1;
    }

    uint4 pre[NLD];
#pragma unroll
    for (int s = 0; s < NLD; s++)
        pre[s] = ldp[s] ? *(const uint4*)(ldp[s]) : make_uint4(0u, 0u, 0u, 0u);
#pragma unroll
    for (int s = 0; s < NLD; s++)
        if (sto[s] >= 0) *(uint4*)(sB[0] + sto[s]) = pre[s];
    __syncthreads();

    const int NK = Cin >> 5;
    for (int kk = 0; kk < NK; kk++) {
        const int cur = kk & 1;
        const int ci0 = kk << 5;
        const bool more = (kk + 1 < NK);
        if (more) {
#pragma unroll
            for (int s = 0; s < NLD; s++)
                pre[s] = ldp[s] ? *(const uint4*)(ldp[s] + ci0 + 32)
                                : make_uint4(0u, 0u, 0u, 0u);
        }
        const unsigned short* sC = sB[cur];
#pragma unroll
        for (int ky = 0; ky < 3; ky++) {
#pragma unroll
            for (int kx = 0; kx < 3; kx++) {
                const int py = PY[ky], dy = DY[ky];
                const int px = PY[kx], dx = DY[kx];
                const int t = ky * 3 + kx;
                const int boff = ((Yl + dy) * (W + 1) + (Xl + dx)) * 40 + kg * 8;
#pragma unroll
                for (int kh = 0; kh < 2; kh++) {
                    const unsigned short* ap =
                        Af + (size_t)t * tStride + (size_t)(((ci0 >> 4) + kh) << 9);
                    v8s B  = *(const v8s*)(sC + boff + kh * 16);
                    v8s A0 = *(const v8s*)(ap);
                    v8s A1 = *(const v8s*)(ap + cbStride);
                    acc[py][px][0] = __builtin_amdgcn_mfma_f32_32x32x16_bf16(A0, B, acc[py][px][0], 0, 0, 0);
                    acc[py][px][1] = __builtin_amdgcn_mfma_f32_32x32x16_bf16(A1, B, acc[py][px][1], 0, 0, 0);
                }
            }
        }
        if (more) {
            unsigned short* sN = sB[cur ^ 1];
#pragma unroll
            for (int s = 0; s < NLD; s++)
                if (sto[s] >= 0) *(uint4*)(sN + sto[s]) = pre[s];
            __syncthreads();
        }
    }
    // epilogue: parity pair (px=0,1) -> consecutive ox -> float2 store
    const int Wo = 2 * W, Ho = 2 * Hin;
    const int yin = y0 + Yl;
#pragma unroll
    for (int py = 0; py < 2; py++) {
        const int oy = 2 * yin + py;
#pragma unroll
        for (int sm = 0; sm < 2; sm++) {
            const int cobase = coB + sm * 32 + 4 * kg;
#pragma unroll
            for (int r = 0; r < 16; r++) {
                int co = cobase + (r & 3) + 8 * (r >> 2);
                float v0 = acc[py][0][sm][r]; v0 = v0 > 0.f ? v0 : 0.f;
                float v1 = acc[py][1][sm][r]; v1 = v1 > 0.f ? v1 : 0.f;
                *(float2*)(out + (((size_t)(b * Cout + co) * Ho + oy) * Wo + 2 * Xl)) =
                    make_float2(v0, v1);
            }
        }
    }
}

// =====================================================================
// Final stride-1 conv: Cout=3, tanh epilogue, fp32
// =====================================================================
__global__ __launch_bounds__(256) void conv_s1_c3_tanh_kernel(
        const float* __restrict__ in, const float* __restrict__ w,
        float* __restrict__ out, int Cin, int H, int W) {
    __shared__ float sIn[8][18][19];
    __shared__ float sW[8][3][9];
    const int tid = threadIdx.x;
    const int r = tid >> 4, c = tid & 15;
    const int ntx = W >> 4;
    const int tx0 = (blockIdx.x % ntx) << 4, ty0 = (blockIdx.x / ntx) << 4;
    const int b = blockIdx.z;
    const int hw = H * W;
    float acc[3] = {0.f, 0.f, 0.f};
    for (int ci0 = 0; ci0 < Cin; ci0 += 8) {
        for (int i = tid; i < 8 * 18 * 18; i += 256) {
            int ci = i / 324, rr = i % 324, ly = rr / 18, lx = rr % 18;
            int gy = ty0 + ly - 1, gx = tx0 + lx - 1;
            float v = 0.f;
            if (gy >= 0 && gy < H && gx >= 0 && gx < W)
                v = in[(size_t)(b * Cin + ci0 + ci) * hw + gy * W + gx];
            sIn[ci][ly][lx] = v;
        }
        for (int i = tid; i < 8 * 3 * 9; i += 256) {
            int ci = i / 27, rr = i % 27, co = rr / 9, k = rr % 9;
            sW[ci][co][k] = w[(size_t)((ci0 + ci) * 3 + co) * 9 + (8 - k)];
        }
        __syncthreads();
#pragma unroll
        for (int ci = 0; ci < 8; ci++) {
            float v00 = sIn[ci][r][c],     v01 = sIn[ci][r][c + 1],     v02 = sIn[ci][r][c + 2];
            float v10 = sIn[ci][r + 1][c], v11 = sIn[ci][r + 1][c + 1], v12 = sIn[ci][r + 1][c + 2];
            float v20 = sIn[ci][r + 2][c], v21 = sIn[ci][r + 2][c + 1], v22 = sIn[ci][r + 2][c + 2];
#pragma unroll
            for (int co = 0; co < 3; co++) {
                const float* wp = &sW[ci][co][0];
                acc[co] += v00 * wp[0] + v01 * wp[1] + v02 * wp[2]
                         + v10 * wp[3] + v11 * wp[4] + v12 * wp[5]
                         + v20 * wp[6] + v21 * wp[7] + v22 * wp[8];
            }
        }
        __syncthreads();
    }
#pragma unroll
    for (int co = 0; co < 3; co++)
        out[(size_t)(b * 3 + co) * hw + (ty0 + r) * W + tx0 + c] = tanhf(acc[co]);
}

// =====================================================================
// Host pipeline. d_out: out | feat_8 | feat_16 | feat_32.
// =====================================================================
extern "C" void kernel_launch(void* const* d_in, const int* in_sizes, int n_in,
                              void* d_out, int out_size, void* d_ws, size_t ws_size,
                              hipStream_t stream) {
    const float* cont = (const float*)d_in[0];
    const float* kv0 = (const float*)d_in[1];
    const float* kh0 = (const float*)d_in[2];
    const float* m0  = (const float*)d_in[3];
    const float* kv1 = (const float*)d_in[4];
    const float* kh1 = (const float*)d_in[5];
    const float* m1  = (const float*)d_in[6];
    const float* kv2 = (const float*)d_in[7];
    const float* kh2 = (const float*)d_in[8];
    const float* m2  = (const float*)d_in[9];
    const float* kv3 = (const float*)d_in[10];
    const float* kh3 = (const float*)d_in[11];
    const float* m3  = (const float*)d_in[12];
    const float* w1  = (const float*)d_in[13];
    const float* w2  = (const float*)d_in[14];
    const float* w3  = (const float*)d_in[15];
    const float* w4  = (const float*)d_in[16];
    const float* w5  = (const float*)d_in[17];
    const float* w6  = (const float*)d_in[18];

    float* out = (float*)d_out;
    float* f8  = out + 1572864;
    float* f16 = out + 2097152;
    float* f32 = out + 18874368;

    char* ws = (char*)d_ws;

    // ---- phase 1 ----
    float* A0 = (float*)ws;                                    // t16 fp32
    unsigned short* X8  = (unsigned short*)(ws + 67108864);
    unsigned short* Wk1 = (unsigned short*)(ws + 68157440);

    // f8 fusion: C=64, 8x8 (LW=3), hw=64 (lhw=6), CH=16
    fusion2_kernel<3><<<dim3(32, 4), 256, 0, stream>>>(
        cont, kv0, kh0, m0, f8, 64, 16, 8, 6);
    nchw_to_nhwc_bf16<<<dim3(8, 128), 256, 8 * 72 * 2, stream>>>(f8, X8, 64, 8, 8, 3, 5);
    repack_w_frag<<<128, 256, 0, stream>>>(w1, Wk1, 64, 512, 0);
    deconv2_mfma<8, 4, 2, 2, 3><<<dim3(1, 4, 128), 256, 0, stream>>>(
        X8, Wk1, A0, 64, 512, 8);
    // f16 fusion: C=512, 16x16 (LW=4), hw=256 (lhw=8), CH=16
    fusion2_kernel<4><<<dim3(128, 32), 256, 0, stream>>>(
        A0, kv1, kh1, m1, f16, 512, 16, 16, 8);

    unsigned short* X16 = (unsigned short*)ws;
    unsigned short* h1b = (unsigned short*)(ws + 67108864);
    unsigned short* Wk3 = (unsigned short*)(ws + 83886080);
    unsigned short* Wk2 = (unsigned short*)(ws + 84475904);
    nchw_to_nhwc_bf16<<<dim3(16, 128), 256, 16 * 520 * 2, stream>>>(
        f16, X16, 512, 16, 16, 4, 8);
    repack_w_frag<<<512, 256, 0, stream>>>(w2, Wk2, 512, 256, 1);
    conv3x3_mfma<16, 8, 4><<<dim3(2, 2, 128), 256, 0, stream>>>(
        X16, Wk2, h1b, 512, 256, 16);
    repack_w_frag<<<128, 256, 0, stream>>>(w3, Wk3, 256, 128, 0);
    float* t32 = (float*)ws;
    deconv2_mfma<16, 2, 2, 2, 4><<<dim3(4, 1, 128), 256, 0, stream>>>(
        h1b, Wk3, t32, 256, 128, 16);
    // f32 fusion: C=128, 32x32 (LW=5), hw=1024 (lhw=10), CH=16
    fusion2_kernel<5><<<dim3(512, 8), 256, 0, stream>>>(
        t32, kv2, kh2, m2, f32, 128, 16, 32, 10);

    // ---- phase 2: batch quarters ----
    unsigned short* Wk4  = (unsigned short*)ws;
    unsigned short* Wk5  = (unsigned short*)(ws + 294912);
    unsigned short* X32q = (unsigned short*)(ws + 524288);
    unsigned short* h2b  = (unsigned short*)(ws + 8912896);
    float* h3q = (float*)(ws + 17301504);
    float* tq  = (float*)(ws + 50855936);
    repack_w_frag<<<64, 256, 0, stream>>>(w4, Wk4, 128, 128, 1);
    repack_w_frag<<<32, 256, 0, stream>>>(w5, Wk5, 128, 64, 0);
    for (int q = 0; q < 4; q++) {
        size_t bo = (size_t)q * 32;
        const float* f32q = f32 + bo * 128 * 1024;
        nchw_to_nhwc_bf16<<<dim3(32, 32), 256, 32 * 136 * 2, stream>>>(
            f32q, X32q, 128, 32, 32, 5, 6);
        conv3x3_mfma<32, 4, 5><<<dim3(8, 1, 32), 256, 0, stream>>>(
            X32q, Wk4, h2b, 128, 128, 32);
        deconv2_mfma<32, 1, 4, 1, 5><<<dim3(8, 1, 32), 256, 0, stream>>>(
            h2b, Wk5, h3q, 128, 64, 32);
        conv_s1_c3_tanh_kernel<<<dim3(16, 1, 32), 256, 0, stream>>>(h3q, w6, tq, 64, 64, 64);
        // out fusion: C=3, 64x64 (LW=6), hw=4096 (lhw=12), CH=3, B_q=32
        fusion2_kernel<6><<<dim3(512, 1), 256, 0, stream>>>(
            tq, kv3 + bo * 5 * 4096, kh3 + bo * 5 * 4096, m3 + bo * 4096,
            out + bo * 3 * 4096, 3, 3, 64, 12);
    }
}

// Round 5
// 984.298 us; speedup vs baseline: 1.2137x; 1.0619x over previous
//
#include <hip/hip_runtime.h>
#include <math.h>

typedef short v8s __attribute__((ext_vector_type(8)));
typedef float v16f __attribute__((ext_vector_type(16)));

// fp32 -> bf16 (RNE)
__device__ inline unsigned short f2bf(float f) {
    union { float f; unsigned u; } c; c.f = f;
    unsigned r = (c.u + 0x7fffu + ((c.u >> 16) & 1u)) >> 16;
    return (unsigned short)r;
}

// =====================================================================
// fusion v2: out = m * sepconv5(feat, kv, kh) + (1-m) * feat   (fp32)
// =====================================================================
template<int LW>
__global__ __launch_bounds__(256) void fusion2_kernel(
        const float* __restrict__ feat, const float* __restrict__ kv,
        const float* __restrict__ kh, const float* __restrict__ m,
        float* __restrict__ out, int C, int CH, int H, int lhw) {
    constexpr int W = 1 << LW;
    const int t = blockIdx.x * 256 + threadIdx.x;
    const int hw = H << LW;
    const int b = t >> lhw;
    const int pix = t & (hw - 1);
    const int x = pix & (W - 1);
    const int y = pix >> LW;
    const int lane = threadIdx.x & 63;
    const int rowbase = (lane & ~(W - 1)) << 2;

    const int c0 = blockIdx.y * CH;

    const float mv = m[(size_t)b * hw + pix];
    float kvv[5], khv[5];
#pragma unroll
    for (int i = 0; i < 5; i++) {
        kvv[i] = kv[((size_t)b * 5 + i) * hw + pix];
        khv[i] = kh[((size_t)b * 5 + i) * hw + pix];
    }
    int idx[5];
#pragma unroll
    for (int j = 0; j < 5; j++) {
        int xx = x + j - 2; xx = xx < 0 ? 0 : (xx >= W ? W - 1 : xx);
        idx[j] = rowbase + (xx << 2);
    }
    int roff[5];
#pragma unroll
    for (int i = 0; i < 5; i++) {
        int yy = y + i - 2; yy = yy < 0 ? 0 : (yy >= H ? H - 1 : yy);
        roff[i] = (yy << LW) + x;
    }

    const float* fbase = feat + ((size_t)b * C + c0) * hw;
    float* obase = out + ((size_t)b * C + c0) * hw + pix;
    const float om = 1.f - mv;

#pragma unroll 4
    for (int cc = 0; cc < CH; cc++) {
        const float* q = fbase + (size_t)cc * hw;
        float s = 0.f;
        float fv = 0.f;
#pragma unroll
        for (int i = 0; i < 5; i++) {
            float v = q[roff[i]];
            if (i == 2) fv = v;
            int vb = __float_as_int(v);
            float h = 0.f;
#pragma unroll
            for (int j = 0; j < 5; j++) {
                float nv = __int_as_float(
                    __builtin_amdgcn_ds_bpermute(idx[j], vb));
                h += nv * khv[j];
            }
            s += kvv[i] * h;
        }
        obase[(size_t)cc * hw] = mv * s + om * fv;
    }
}

// =====================================================================
// NCHW fp32 -> NHWC bf16 transpose. One block per (y, b).
// =====================================================================
__global__ __launch_bounds__(256) void nchw_to_nhwc_bf16(
        const float* __restrict__ in, unsigned short* __restrict__ out,
        int C, int H, int W, int lw, int lc2) {
    extern __shared__ unsigned short sm_t[];
    const int y = blockIdx.x, b = blockIdx.y;
    const int Cp = C + 8;
    const int tid = threadIdx.x;
    for (int i = tid; i < C * W; i += 256) {
        int x = i & (W - 1), c = i >> lw;
        float v = in[(((size_t)b * C + c) * H + y) * W + x];
        sm_t[x * Cp + c] = f2bf(v);
    }
    __syncthreads();
    const unsigned* s32 = (const unsigned*)sm_t;
    unsigned* o32 = (unsigned*)(out + (((size_t)b * H + y) * W) * C);
    const int n32 = (W * C) >> 1;
    for (int i = tid; i < n32; i += 256) {
        int x = i >> lc2;
        int c2 = i - (x << lc2);
        o32[i] = s32[x * (Cp >> 1) + c2];
    }
}

// =====================================================================
// Repack [Cin][Cout][3][3] fp32 -> MFMA-fragment-ordered bf16:
//   [t][co>>5][ci>>4][ (kg=((ci>>3)&1))*32 + (co&31) ][ci&7]
// Wave A-load = base + lane*16B, one coalesced 1KiB read.
// flip=1: tap t stores source index 8-t (deconv-as-conv, stride 1).
// =====================================================================
__global__ __launch_bounds__(256) void repack_w_frag(
        const float* __restrict__ w, unsigned short* __restrict__ wk,
        int Cin, int Cout, int flip) {
    int idx = blockIdx.x * 256 + threadIdx.x;
    if (idx >= Cin * Cout) return;
    int ci = idx / Cout, co = idx - ci * Cout;
    const float* src = w + (size_t)idx * 9;
    const int nCb = Cout >> 5, nH = Cin >> 4;
    const size_t inner = (size_t)((((ci >> 3) & 1) * 32 + (co & 31)) * 8 + (ci & 7));
#pragma unroll
    for (int k = 0; k < 9; k++) {
        int t = flip ? (8 - k) : k;
        size_t blk = ((size_t)t * nCb + (co >> 5)) * nH + (ci >> 4);
        wk[(blk << 9) + inner] = f2bf(src[k]);
    }
}

// =====================================================================
// 3x3 conv MFMA implicit GEMM + ReLU. Double-buffered LDS (async-stage
// split) + explicit register software-pipeline of the operand stream:
// A fragments depth-3 (covers ~2 stages of L2 latency), B fragments
// depth-2 (covers LDS latency). Accumulation order unchanged.
// =====================================================================
template<int W, int TH, int LW>
__global__ __launch_bounds__(256) void conv3x3_mfma(
        const unsigned short* __restrict__ X,
        const unsigned short* __restrict__ Wk,
        unsigned short* __restrict__ out, int Cin, int Cout, int H) {
    constexpr int TP = (TH + 2) * (W + 2);
    constexpr int NIT = TP * 4;
    constexpr int NLD = (NIT + 255) / 256;
    __shared__ unsigned short sB[2][TP * 40];
    const int tid = threadIdx.x;
    const int lane = tid & 63, wv = tid >> 6;
    const int wm = wv >> 1, wn = wv & 1;
    const int y0 = blockIdx.x * TH;
    const int coB = blockIdx.y * 128 + wm * 64;
    const int b = blockIdx.z;
    const int n = lane & 31, kg = lane >> 5;
    const int p0 = wn * 64 + n, p1 = p0 + 32;
    const int r0 = p0 >> LW, c0 = p0 & (W - 1);
    const int r1 = p1 >> LW, c1 = p1 & (W - 1);
    const int bo0 = (r0 * (W + 2) + c0) * 40 + kg * 8;
    const int bo1 = (r1 * (W + 2) + c1) * 40 + kg * 8;
    v16f acc00 = {}, acc01 = {}, acc10 = {}, acc11 = {};
    const size_t cbStride = (size_t)(Cin >> 4) << 9;
    const size_t tStride  = (size_t)(Cout >> 5) * cbStride;
    const unsigned short* Af = Wk + (size_t)(coB >> 5) * cbStride + (lane << 3);
    const unsigned short* Xb = X + (size_t)b * H * W * Cin;

    // staging descriptors (K-invariant)
    const unsigned short* ldp[NLD];
    int sto[NLD];
#pragma unroll
    for (int s = 0; s < NLD; s++) {
        int i = tid + s * 256;
        bool slot = (i < NIT);
        int pix = i >> 2, part = i & 3;
        int py = pix / (W + 2), px = pix - py * (W + 2);
        int gy = y0 + py - 1, gx = px - 1;
        bool ok = slot && gy >= 0 && gy < H && (unsigned)gx < (unsigned)W;
        ldp[s] = ok ? Xb + ((size_t)(gy * W + gx)) * Cin + part * 8 : nullptr;
        sto[s] = slot ? pix * 40 + part * 8 : -1;
    }

    // prologue: stage tile 0 into buf 0
    uint4 pre[NLD];
#pragma unroll
    for (int s = 0; s < NLD; s++)
        pre[s] = ldp[s] ? *(const uint4*)(ldp[s]) : make_uint4(0u, 0u, 0u, 0u);
#pragma unroll
    for (int s = 0; s < NLD; s++)
        if (sto[s] >= 0) *(uint4*)(sB[0] + sto[s]) = pre[s];
    __syncthreads();

    const int NK = Cin >> 5;
    for (int kk = 0; kk < NK; kk++) {
        const int cur = kk & 1;
        const int ci0 = kk << 5;
        const bool more = (kk + 1 < NK);
        if (more) {
#pragma unroll
            for (int s = 0; s < NLD; s++)
                pre[s] = ldp[s] ? *(const uint4*)(ldp[s] + ci0 + 32)
                                : make_uint4(0u, 0u, 0u, 0u);
        }
        const unsigned short* sC = sB[cur];
        const unsigned short* Abase2 = Af + ((size_t)(ci0 >> 4) << 9);

        auto ldA = [&](int s, v8s &a0, v8s &a1) {
            const int t = s >> 1, kh = s & 1;
            const unsigned short* ap = Abase2 + (size_t)t * tStride + (kh << 9);
            a0 = *(const v8s*)(ap);
            a1 = *(const v8s*)(ap + cbStride);
        };
        auto ldB = [&](int s, v8s &b0v, v8s &b1v) {
            const int t = s >> 1, kh = s & 1;
            const int ky = t / 3, kx = t - ky * 3;
            const int off = (ky * (W + 2) + kx) * 40 + kh * 16;
            b0v = *(const v8s*)(sC + bo0 + off);
            b1v = *(const v8s*)(sC + bo1 + off);
        };

        v8s A0p[3], A1p[3], B0p[2], B1p[2];
        ldA(0, A0p[0], A1p[0]);
        ldA(1, A0p[1], A1p[1]);
        ldA(2, A0p[2], A1p[2]);
        ldB(0, B0p[0], B1p[0]);
#pragma unroll
        for (int s = 0; s < 18; s++) {
            const int ca = s % 3, cb = s & 1;
            if (s + 1 < 18) ldB(s + 1, B0p[cb ^ 1], B1p[cb ^ 1]);
            acc00 = __builtin_amdgcn_mfma_f32_32x32x16_bf16(A0p[ca], B0p[cb], acc00, 0, 0, 0);
            acc01 = __builtin_amdgcn_mfma_f32_32x32x16_bf16(A0p[ca], B1p[cb], acc01, 0, 0, 0);
            acc10 = __builtin_amdgcn_mfma_f32_32x32x16_bf16(A1p[ca], B0p[cb], acc10, 0, 0, 0);
            acc11 = __builtin_amdgcn_mfma_f32_32x32x16_bf16(A1p[ca], B1p[cb], acc11, 0, 0, 0);
            if (s + 3 < 18) ldA(s + 3, A0p[ca], A1p[ca]);
        }

        if (more) {
            unsigned short* sN = sB[cur ^ 1];
#pragma unroll
            for (int s = 0; s < NLD; s++)
                if (sto[s] >= 0) *(uint4*)(sN + sto[s]) = pre[s];
            __syncthreads();
        }
    }
    // C/D: col=lane&31 -> pixel, row r -> co = base + (r&3) + 8*(r>>2) + 4*kg
    unsigned short* ob = out + (size_t)b * H * W * Cout;
#pragma unroll
    for (int sm = 0; sm < 2; sm++) {
        v16f a0 = sm ? acc10 : acc00;
        v16f a1 = sm ? acc11 : acc01;
        const int cobase = coB + sm * 32 + 4 * kg;
        unsigned short* q0p = ob + ((size_t)((y0 + r0) * W + c0)) * Cout + cobase;
        unsigned short* q1p = ob + ((size_t)((y0 + r1) * W + c1)) * Cout + cobase;
#pragma unroll
        for (int r2 = 0; r2 < 4; r2++) {
            ushort4 q0, q1; float v;
            v = a0[4 * r2 + 0]; v = v > 0.f ? v : 0.f; q0.x = f2bf(v);
            v = a0[4 * r2 + 1]; v = v > 0.f ? v : 0.f; q0.y = f2bf(v);
            v = a0[4 * r2 + 2]; v = v > 0.f ? v : 0.f; q0.z = f2bf(v);
            v = a0[4 * r2 + 3]; v = v > 0.f ? v : 0.f; q0.w = f2bf(v);
            *(ushort4*)(q0p + 8 * r2) = q0;
            v = a1[4 * r2 + 0]; v = v > 0.f ? v : 0.f; q1.x = f2bf(v);
            v = a1[4 * r2 + 1]; v = v > 0.f ? v : 0.f; q1.y = f2bf(v);
            v = a1[4 * r2 + 2]; v = v > 0.f ? v : 0.f; q1.z = f2bf(v);
            v = a1[4 * r2 + 3]; v = v > 0.f ? v : 0.f; q1.w = f2bf(v);
            *(ushort4*)(q1p + 8 * r2) = q1;
        }
    }
}

// =====================================================================
// stride-2 deconv (k=3,p=1,op=1) as 4 parity convs on MFMA + ReLU.
// Same dbuf + register software-pipeline structure.
// =====================================================================
template<int W, int TH, int NWN, int NWM, int LW>
__global__ __launch_bounds__(256) void deconv2_mfma(
        const unsigned short* __restrict__ X,
        const unsigned short* __restrict__ Wk,
        float* __restrict__ out, int Cin, int Cout, int Hin) {
    constexpr int ROWS = NWN * TH + 1;
    constexpr int NPIX = ROWS * (W + 1);
    constexpr int NIT = NPIX * 4;
    constexpr int NLD = (NIT + 255) / 256;
    __shared__ unsigned short sB[2][NPIX * 40];
    const int tid = threadIdx.x;
    const int lane = tid & 63, wv = tid >> 6;
    const int wm = wv / NWN, wn = wv % NWN;
    const int n = lane & 31, kg = lane >> 5;
    const int y0 = blockIdx.x * (NWN * TH);
    const int coB = (blockIdx.y * NWM + wm) * 64;
    const int b = blockIdx.z;
    const int Yl = wn * TH + (n >> LW);
    const int Xl = n & (W - 1);
    v16f zero = {};
    v16f acc[2][2][2];
#pragma unroll
    for (int i = 0; i < 2; i++)
#pragma unroll
        for (int j = 0; j < 2; j++)
#pragma unroll
            for (int s = 0; s < 2; s++) acc[i][j][s] = zero;
    const unsigned short* Xb = X + (size_t)b * Hin * W * Cin;
    const size_t cbStride = (size_t)(Cin >> 4) << 9;
    const size_t tStride  = (size_t)(Cout >> 5) * cbStride;
    const unsigned short* Af = Wk + (size_t)(coB >> 5) * cbStride + (lane << 3);
    const int PY[3] = {1, 0, 1}, DY[3] = {1, 0, 0};

    const unsigned short* ldp[NLD];
    int sto[NLD];
#pragma unroll
    for (int s = 0; s < NLD; s++) {
        int i = tid + s * 256;
        bool slot = (i < NIT);
        int pix = i >> 2, part = i & 3;
        int py_ = pix / (W + 1), px_ = pix - py_ * (W + 1);
        int gy = y0 + py_, gx = px_;
        bool ok = slot && gy < Hin && gx < W;
        ldp[s] = ok ? Xb + ((size_t)(gy * W + gx)) * Cin + part * 8 : nullptr;
        sto[s] = slot ? pix * 40 + part * 8 : -1;
    }

    uint4 pre[NLD];
#pragma unroll
    for (int s = 0; s < NLD; s++)
        pre[s] = ldp[s] ? *(const uint4*)(ldp[s]) : make_uint4(0u, 0u, 0u, 0u);
#pragma unroll
    for (int s = 0; s < NLD; s++)
        if (sto[s] >= 0) *(uint4*)(sB[0] + sto[s]) = pre[s];
    __syncthreads();

    const int NK = Cin >> 5;
    for (int kk = 0; kk < NK; kk++) {
        const int cur = kk & 1;
        const int ci0 = kk << 5;
        const bool more = (kk + 1 < NK);
        if (more) {
#pragma unroll
            for (int s = 0; s < NLD; s++)
                pre[s] = ldp[s] ? *(const uint4*)(ldp[s] + ci0 + 32)
                                : make_uint4(0u, 0u, 0u, 0u);
        }
        const unsigned short* sC = sB[cur];
        const unsigned short* Abase2 = Af + ((size_t)(ci0 >> 4) << 9);

        auto ldA = [&](int s, v8s &a0, v8s &a1) {
            const int t = s >> 1, kh = s & 1;
            const unsigned short* ap = Abase2 + (size_t)t * tStride + (kh << 9);
            a0 = *(const v8s*)(ap);
            a1 = *(const v8s*)(ap + cbStride);
        };
        auto ldB = [&](int s, v8s &bv) {
            const int t = s >> 1, kh = s & 1;
            const int ky = t / 3, kx = t - ky * 3;
            const int boff = ((Yl + DY[ky]) * (W + 1) + (Xl + DY[kx])) * 40
                             + kg * 8 + kh * 16;
            bv = *(const v8s*)(sC + boff);
        };

        v8s A0p[3], A1p[3], Bp[2];
        ldA(0, A0p[0], A1p[0]);
        ldA(1, A0p[1], A1p[1]);
        ldA(2, A0p[2], A1p[2]);
        ldB(0, Bp[0]);
#pragma unroll
        for (int s = 0; s < 18; s++) {
            const int ca = s % 3, cb = s & 1;
            if (s + 1 < 18) ldB(s + 1, Bp[cb ^ 1]);
            const int t = s >> 1;
            const int ky = t / 3, kx = t - ky * 3;
            const int py = PY[ky], px = PY[kx];
            acc[py][px][0] = __builtin_amdgcn_mfma_f32_32x32x16_bf16(A0p[ca], Bp[cb], acc[py][px][0], 0, 0, 0);
            acc[py][px][1] = __builtin_amdgcn_mfma_f32_32x32x16_bf16(A1p[ca], Bp[cb], acc[py][px][1], 0, 0, 0);
            if (s + 3 < 18) ldA(s + 3, A0p[ca], A1p[ca]);
        }

        if (more) {
            unsigned short* sN = sB[cur ^ 1];
#pragma unroll
            for (int s = 0; s < NLD; s++)
                if (sto[s] >= 0) *(uint4*)(sN + sto[s]) = pre[s];
            __syncthreads();
        }
    }
    // epilogue: parity pair (px=0,1) -> consecutive ox -> float2 store
    const int Wo = 2 * W, Ho = 2 * Hin;
    const int yin = y0 + Yl;
#pragma unroll
    for (int py = 0; py < 2; py++) {
        const int oy = 2 * yin + py;
#pragma unroll
        for (int sm = 0; sm < 2; sm++) {
            const int cobase = coB + sm * 32 + 4 * kg;
#pragma unroll
            for (int r = 0; r < 16; r++) {
                int co = cobase + (r & 3) + 8 * (r >> 2);
                float v0 = acc[py][0][sm][r]; v0 = v0 > 0.f ? v0 : 0.f;
                float v1 = acc[py][1][sm][r]; v1 = v1 > 0.f ? v1 : 0.f;
                *(float2*)(out + (((size_t)(b * Cout + co) * Ho + oy) * Wo + 2 * Xl)) =
                    make_float2(v0, v1);
            }
        }
    }
}

// =====================================================================
// Final stride-1 conv: Cout=3, tanh epilogue, fp32
// =====================================================================
__global__ __launch_bounds__(256) void conv_s1_c3_tanh_kernel(
        const float* __restrict__ in, const float* __restrict__ w,
        float* __restrict__ out, int Cin, int H, int W) {
    __shared__ float sIn[8][18][19];
    __shared__ float sW[8][3][9];
    const int tid = threadIdx.x;
    const int r = tid >> 4, c = tid & 15;
    const int ntx = W >> 4;
    const int tx0 = (blockIdx.x % ntx) << 4, ty0 = (blockIdx.x / ntx) << 4;
    const int b = blockIdx.z;
    const int hw = H * W;
    float acc[3] = {0.f, 0.f, 0.f};
    for (int ci0 = 0; ci0 < Cin; ci0 += 8) {
        for (int i = tid; i < 8 * 18 * 18; i += 256) {
            int ci = i / 324, rr = i % 324, ly = rr / 18, lx = rr % 18;
            int gy = ty0 + ly - 1, gx = tx0 + lx - 1;
            float v = 0.f;
            if (gy >= 0 && gy < H && gx >= 0 && gx < W)
                v = in[(size_t)(b * Cin + ci0 + ci) * hw + gy * W + gx];
            sIn[ci][ly][lx] = v;
        }
        for (int i = tid; i < 8 * 3 * 9; i += 256) {
            int ci = i / 27, rr = i % 27, co = rr / 9, k = rr % 9;
            sW[ci][co][k] = w[(size_t)((ci0 + ci) * 3 + co) * 9 + (8 - k)];
        }
        __syncthreads();
#pragma unroll
        for (int ci = 0; ci < 8; ci++) {
            float v00 = sIn[ci][r][c],     v01 = sIn[ci][r][c + 1],     v02 = sIn[ci][r][c + 2];
            float v10 = sIn[ci][r + 1][c], v11 = sIn[ci][r + 1][c + 1], v12 = sIn[ci][r + 1][c + 2];
            float v20 = sIn[ci][r + 2][c], v21 = sIn[ci][r + 2][c + 1], v22 = sIn[ci][r + 2][c + 2];
#pragma unroll
            for (int co = 0; co < 3; co++) {
                const float* wp = &sW[ci][co][0];
                acc[co] += v00 * wp[0] + v01 * wp[1] + v02 * wp[2]
                         + v10 * wp[3] + v11 * wp[4] + v12 * wp[5]
                         + v20 * wp[6] + v21 * wp[7] + v22 * wp[8];
            }
        }
        __syncthreads();
    }
#pragma unroll
    for (int co = 0; co < 3; co++)
        out[(size_t)(b * 3 + co) * hw + (ty0 + r) * W + tx0 + c] = tanhf(acc[co]);
}

// =====================================================================
// Host pipeline. d_out: out | feat_8 | feat_16 | feat_32.
// =====================================================================
extern "C" void kernel_launch(void* const* d_in, const int* in_sizes, int n_in,
                              void* d_out, int out_size, void* d_ws, size_t ws_size,
                              hipStream_t stream) {
    const float* cont = (const float*)d_in[0];
    const float* kv0 = (const float*)d_in[1];
    const float* kh0 = (const float*)d_in[2];
    const float* m0  = (const float*)d_in[3];
    const float* kv1 = (const float*)d_in[4];
    const float* kh1 = (const float*)d_in[5];
    const float* m1  = (const float*)d_in[6];
    const float* kv2 = (const float*)d_in[7];
    const float* kh2 = (const float*)d_in[8];
    const float* m2  = (const float*)d_in[9];
    const float* kv3 = (const float*)d_in[10];
    const float* kh3 = (const float*)d_in[11];
    const float* m3  = (const float*)d_in[12];
    const float* w1  = (const float*)d_in[13];
    const float* w2  = (const float*)d_in[14];
    const float* w3  = (const float*)d_in[15];
    const float* w4  = (const float*)d_in[16];
    const float* w5  = (const float*)d_in[17];
    const float* w6  = (const float*)d_in[18];

    float* out = (float*)d_out;
    float* f8  = out + 1572864;
    float* f16 = out + 2097152;
    float* f32 = out + 18874368;

    char* ws = (char*)d_ws;

    // ---- phase 1 ----
    float* A0 = (float*)ws;                                    // t16 fp32
    unsigned short* X8  = (unsigned short*)(ws + 67108864);
    unsigned short* Wk1 = (unsigned short*)(ws + 68157440);

    fusion2_kernel<3><<<dim3(32, 4), 256, 0, stream>>>(
        cont, kv0, kh0, m0, f8, 64, 16, 8, 6);
    nchw_to_nhwc_bf16<<<dim3(8, 128), 256, 8 * 72 * 2, stream>>>(f8, X8, 64, 8, 8, 3, 5);
    repack_w_frag<<<128, 256, 0, stream>>>(w1, Wk1, 64, 512, 0);
    deconv2_mfma<8, 4, 2, 2, 3><<<dim3(1, 4, 128), 256, 0, stream>>>(
        X8, Wk1, A0, 64, 512, 8);
    fusion2_kernel<4><<<dim3(128, 32), 256, 0, stream>>>(
        A0, kv1, kh1, m1, f16, 512, 16, 16, 8);

    unsigned short* X16 = (unsigned short*)ws;
    unsigned short* h1b = (unsigned short*)(ws + 67108864);
    unsigned short* Wk3 = (unsigned short*)(ws + 83886080);
    unsigned short* Wk2 = (unsigned short*)(ws + 84475904);
    nchw_to_nhwc_bf16<<<dim3(16, 128), 256, 16 * 520 * 2, stream>>>(
        f16, X16, 512, 16, 16, 4, 8);
    repack_w_frag<<<512, 256, 0, stream>>>(w2, Wk2, 512, 256, 1);
    conv3x3_mfma<16, 8, 4><<<dim3(2, 2, 128), 256, 0, stream>>>(
        X16, Wk2, h1b, 512, 256, 16);
    repack_w_frag<<<128, 256, 0, stream>>>(w3, Wk3, 256, 128, 0);
    float* t32 = (float*)ws;
    deconv2_mfma<16, 2, 2, 2, 4><<<dim3(4, 1, 128), 256, 0, stream>>>(
        h1b, Wk3, t32, 256, 128, 16);
    fusion2_kernel<5><<<dim3(512, 8), 256, 0, stream>>>(
        t32, kv2, kh2, m2, f32, 128, 16, 32, 10);

    // ---- phase 2 ----
    if (ws_size >= (size_t)102760448) {
        // full-batch conv3x3; deconv2/conv_s1/fusion still per quarter
        unsigned short* Wk4 = (unsigned short*)ws;
        unsigned short* Wk5 = (unsigned short*)(ws + 294912);
        unsigned short* X32 = (unsigned short*)(ws + 524288);      // 33.55MB
        unsigned short* h2b = (unsigned short*)(ws + 34078720);    // 33.55MB
        float* h3q = (float*)(ws + 67633152);                      // 33.55MB
        float* tq  = (float*)(ws + 101187584);                     // 1.57MB
        repack_w_frag<<<64, 256, 0, stream>>>(w4, Wk4, 128, 128, 1);
        repack_w_frag<<<32, 256, 0, stream>>>(w5, Wk5, 128, 64, 0);
        nchw_to_nhwc_bf16<<<dim3(32, 128), 256, 32 * 136 * 2, stream>>>(
            f32, X32, 128, 32, 32, 5, 6);
        conv3x3_mfma<32, 4, 5><<<dim3(8, 1, 128), 256, 0, stream>>>(
            X32, Wk4, h2b, 128, 128, 32);
        for (int q = 0; q < 4; q++) {
            size_t bo = (size_t)q * 32;
            deconv2_mfma<32, 1, 4, 1, 5><<<dim3(8, 1, 32), 256, 0, stream>>>(
                h2b + bo * 131072, Wk5, h3q, 128, 64, 32);
            conv_s1_c3_tanh_kernel<<<dim3(16, 1, 32), 256, 0, stream>>>(h3q, w6, tq, 64, 64, 64);
            fusion2_kernel<6><<<dim3(512, 1), 256, 0, stream>>>(
                tq, kv3 + bo * 5 * 4096, kh3 + bo * 5 * 4096, m3 + bo * 4096,
                out + bo * 3 * 4096, 3, 3, 64, 12);
        }
    } else {
        // quarter path (original layout)
        unsigned short* Wk4  = (unsigned short*)ws;
        unsigned short* Wk5  = (unsigned short*)(ws + 294912);
        unsigned short* X32q = (unsigned short*)(ws + 524288);
        unsigned short* h2b  = (unsigned short*)(ws + 8912896);
        float* h3q = (float*)(ws + 17301504);
        float* tq  = (float*)(ws + 50855936);
        repack_w_frag<<<64, 256, 0, stream>>>(w4, Wk4, 128, 128, 1);
        repack_w_frag<<<32, 256, 0, stream>>>(w5, Wk5, 128, 64, 0);
        for (int q = 0; q < 4; q++) {
            size_t bo = (size_t)q * 32;
            const float* f32q = f32 + bo * 128 * 1024;
            nchw_to_nhwc_bf16<<<dim3(32, 32), 256, 32 * 136 * 2, stream>>>(
                f32q, X32q, 128, 32, 32, 5, 6);
            conv3x3_mfma<32, 4, 5><<<dim3(8, 1, 32), 256, 0, stream>>>(
                X32q, Wk4, h2b, 128, 128, 32);
            deconv2_mfma<32, 1, 4, 1, 5><<<dim3(8, 1, 32), 256, 0, stream>>>(
                h2b, Wk5, h3q, 128, 64, 32);
            conv_s1_c3_tanh_kernel<<<dim3(16, 1, 32), 256, 0, stream>>>(h3q, w6, tq, 64, 64, 64);
            fusion2_kernel<6><<<dim3(512, 1), 256, 0, stream>>>(
                tq, kv3 + bo * 5 * 4096, kh3 + bo * 5 * 4096, m3 + bo * 4096,
                out + bo * 3 * 4096, 3, 3, 64, 12);
        }
    }
}

// Round 6
// 933.841 us; speedup vs baseline: 1.2793x; 1.0540x over previous
//
#include <hip/hip_runtime.h>
#include <math.h>

typedef short v8s __attribute__((ext_vector_type(8)));
typedef float v16f __attribute__((ext_vector_type(16)));

// fp32 -> bf16 (RNE)
__device__ inline unsigned short f2bf(float f) {
    union { float f; unsigned u; } c; c.f = f;
    unsigned r = (c.u + 0x7fffu + ((c.u >> 16) & 1u)) >> 16;
    return (unsigned short)r;
}

// =====================================================================
// fusion v3: out = m * sepconv5(feat, kv, kh) + (1-m) * feat   (fp32)
// One thread per (b,pixel), CH channels (template). Horizontal taps via
// ds_bpermute; vertical clamp in address. OPTIONAL second output: the
// NHWC bf16 tensor (xout != nullptr, CH==16) -- fuses the former
// nchw_to_nhwc_bf16 pass into this kernel (identical f2bf values).
// =====================================================================
template<int LW, int CH>
__global__ __launch_bounds__(256) void fusion2_kernel(
        const float* __restrict__ feat, const float* __restrict__ kv,
        const float* __restrict__ kh, const float* __restrict__ m,
        float* __restrict__ out, unsigned short* __restrict__ xout,
        int C, int H, int lhw) {
    constexpr int W = 1 << LW;
    const int t = blockIdx.x * 256 + threadIdx.x;
    const int hw = H << LW;
    const int b = t >> lhw;
    const int pix = t & (hw - 1);
    const int x = pix & (W - 1);
    const int y = pix >> LW;
    const int lane = threadIdx.x & 63;
    const int rowbase = (lane & ~(W - 1)) << 2;

    const int c0 = blockIdx.y * CH;

    const float mv = m[(size_t)b * hw + pix];
    float kvv[5], khv[5];
#pragma unroll
    for (int i = 0; i < 5; i++) {
        kvv[i] = kv[((size_t)b * 5 + i) * hw + pix];
        khv[i] = kh[((size_t)b * 5 + i) * hw + pix];
    }
    int idx[5];
#pragma unroll
    for (int j = 0; j < 5; j++) {
        int xx = x + j - 2; xx = xx < 0 ? 0 : (xx >= W ? W - 1 : xx);
        idx[j] = rowbase + (xx << 2);
    }
    int roff[5];
#pragma unroll
    for (int i = 0; i < 5; i++) {
        int yy = y + i - 2; yy = yy < 0 ? 0 : (yy >= H ? H - 1 : yy);
        roff[i] = (yy << LW) + x;
    }

    const float* fbase = feat + ((size_t)b * C + c0) * hw;
    float* obase = out + ((size_t)b * C + c0) * hw + pix;
    const float om = 1.f - mv;

    unsigned pk[(CH + 1) / 2];
#pragma unroll
    for (int i = 0; i < (CH + 1) / 2; i++) pk[i] = 0u;

#pragma unroll
    for (int cc = 0; cc < CH; cc++) {
        const float* q = fbase + (size_t)cc * hw;
        float s = 0.f;
        float fv = 0.f;
#pragma unroll
        for (int i = 0; i < 5; i++) {
            float v = q[roff[i]];
            if (i == 2) fv = v;
            int vb = __float_as_int(v);
            float h = 0.f;
#pragma unroll
            for (int j = 0; j < 5; j++) {
                float nv = __int_as_float(
                    __builtin_amdgcn_ds_bpermute(idx[j], vb));
                h += nv * khv[j];
            }
            s += kvv[i] * h;
        }
        float r = mv * s + om * fv;
        obase[(size_t)cc * hw] = r;
        if constexpr (CH == 16)
            pk[cc >> 1] |= (unsigned)f2bf(r) << ((cc & 1) * 16);
    }
    if constexpr (CH == 16) {
        if (xout) {
            unsigned short* xp = xout + ((size_t)b * hw + pix) * C + c0;
            *(uint4*)(xp)     = make_uint4(pk[0], pk[1], pk[2], pk[3]);
            *(uint4*)(xp + 8) = make_uint4(pk[4], pk[5], pk[6], pk[7]);
        }
    }
}

// =====================================================================
// NCHW fp32 -> NHWC bf16 transpose (fallback path only).
// =====================================================================
__global__ __launch_bounds__(256) void nchw_to_nhwc_bf16(
        const float* __restrict__ in, unsigned short* __restrict__ out,
        int C, int H, int W, int lw, int lc2) {
    extern __shared__ unsigned short sm_t[];
    const int y = blockIdx.x, b = blockIdx.y;
    const int Cp = C + 8;
    const int tid = threadIdx.x;
    for (int i = tid; i < C * W; i += 256) {
        int x = i & (W - 1), c = i >> lw;
        float v = in[(((size_t)b * C + c) * H + y) * W + x];
        sm_t[x * Cp + c] = f2bf(v);
    }
    __syncthreads();
    const unsigned* s32 = (const unsigned*)sm_t;
    unsigned* o32 = (unsigned*)(out + (((size_t)b * H + y) * W) * C);
    const int n32 = (W * C) >> 1;
    for (int i = tid; i < n32; i += 256) {
        int x = i >> lc2;
        int c2 = i - (x << lc2);
        o32[i] = s32[x * (Cp >> 1) + c2];
    }
}

// =====================================================================
// Repack [Cin][Cout][3][3] fp32 -> MFMA-fragment-ordered bf16:
//   [t][co>>5][ci>>4][ (kg=((ci>>3)&1))*32 + (co&31) ][ci&7]
// Wave A-load = base + lane*16B, one coalesced 1KiB read.
// flip=1: tap t stores source index 8-t (deconv-as-conv, stride 1).
// =====================================================================
__global__ __launch_bounds__(256) void repack_w_frag(
        const float* __restrict__ w, unsigned short* __restrict__ wk,
        int Cin, int Cout, int flip) {
    int idx = blockIdx.x * 256 + threadIdx.x;
    if (idx >= Cin * Cout) return;
    int ci = idx / Cout, co = idx - ci * Cout;
    const float* src = w + (size_t)idx * 9;
    const int nCb = Cout >> 5, nH = Cin >> 4;
    const size_t inner = (size_t)((((ci >> 3) & 1) * 32 + (co & 31)) * 8 + (ci & 7));
#pragma unroll
    for (int k = 0; k < 9; k++) {
        int t = flip ? (8 - k) : k;
        size_t blk = ((size_t)t * nCb + (co >> 5)) * nH + (ci >> 4);
        wk[(blk << 9) + inner] = f2bf(src[k]);
    }
}

// =====================================================================
// 3x3 conv (pad 1, pre-flipped weights) MFMA implicit GEMM + ReLU.
// Double-buffered LDS, async-stage split, ONE barrier per K-iter.
// Inner loop is the simple 9-tap form (compiler schedules best).
// =====================================================================
template<int W, int TH, int LW>
__global__ __launch_bounds__(256) void conv3x3_mfma(
        const unsigned short* __restrict__ X,
        const unsigned short* __restrict__ Wk,
        unsigned short* __restrict__ out, int Cin, int Cout, int H) {
    constexpr int TP = (TH + 2) * (W + 2);
    constexpr int NIT = TP * 4;
    constexpr int NLD = (NIT + 255) / 256;
    __shared__ unsigned short sB[2][TP * 40];
    const int tid = threadIdx.x;
    const int lane = tid & 63, wv = tid >> 6;
    const int wm = wv >> 1, wn = wv & 1;
    const int y0 = blockIdx.x * TH;
    const int coB = blockIdx.y * 128 + wm * 64;
    const int b = blockIdx.z;
    const int n = lane & 31, kg = lane >> 5;
    const int p0 = wn * 64 + n, p1 = p0 + 32;
    const int r0 = p0 >> LW, c0 = p0 & (W - 1);
    const int r1 = p1 >> LW, c1 = p1 & (W - 1);
    const int bo0 = (r0 * (W + 2) + c0) * 40 + kg * 8;
    const int bo1 = (r1 * (W + 2) + c1) * 40 + kg * 8;
    v16f acc00 = {}, acc01 = {}, acc10 = {}, acc11 = {};
    const size_t cbStride = (size_t)(Cin >> 4) << 9;
    const size_t tStride  = (size_t)(Cout >> 5) * cbStride;
    const unsigned short* Af = Wk + (size_t)(coB >> 5) * cbStride + (lane << 3);
    const unsigned short* Xb = X + (size_t)b * H * W * Cin;

    const unsigned short* ldp[NLD];
    int sto[NLD];
#pragma unroll
    for (int s = 0; s < NLD; s++) {
        int i = tid + s * 256;
        bool slot = (i < NIT);
        int pix = i >> 2, part = i & 3;
        int py = pix / (W + 2), px = pix - py * (W + 2);
        int gy = y0 + py - 1, gx = px - 1;
        bool ok = slot && gy >= 0 && gy < H && (unsigned)gx < (unsigned)W;
        ldp[s] = ok ? Xb + ((size_t)(gy * W + gx)) * Cin + part * 8 : nullptr;
        sto[s] = slot ? pix * 40 + part * 8 : -1;
    }

    uint4 pre[NLD];
#pragma unroll
    for (int s = 0; s < NLD; s++)
        pre[s] = ldp[s] ? *(const uint4*)(ldp[s]) : make_uint4(0u, 0u, 0u, 0u);
#pragma unroll
    for (int s = 0; s < NLD; s++)
        if (sto[s] >= 0) *(uint4*)(sB[0] + sto[s]) = pre[s];
    __syncthreads();

    const int NK = Cin >> 5;
    for (int kk = 0; kk < NK; kk++) {
        const int cur = kk & 1;
        const int ci0 = kk << 5;
        const bool more = (kk + 1 < NK);
        if (more) {
#pragma unroll
            for (int s = 0; s < NLD; s++)
                pre[s] = ldp[s] ? *(const uint4*)(ldp[s] + ci0 + 32)
                                : make_uint4(0u, 0u, 0u, 0u);
        }
        const unsigned short* sC = sB[cur];
#pragma unroll
        for (int t = 0; t < 9; t++) {
            const int ky = t / 3, kx = t - ky * 3;
            const int toff = (ky * (W + 2) + kx) * 40;
#pragma unroll
            for (int kh = 0; kh < 2; kh++) {
                const unsigned short* ap =
                    Af + (size_t)t * tStride + (size_t)(((ci0 >> 4) + kh) << 9);
                v8s A0 = *(const v8s*)(ap);
                v8s A1 = *(const v8s*)(ap + cbStride);
                v8s B0 = *(const v8s*)(sC + bo0 + toff + kh * 16);
                v8s B1 = *(const v8s*)(sC + bo1 + toff + kh * 16);
                acc00 = __builtin_amdgcn_mfma_f32_32x32x16_bf16(A0, B0, acc00, 0, 0, 0);
                acc01 = __builtin_amdgcn_mfma_f32_32x32x16_bf16(A0, B1, acc01, 0, 0, 0);
                acc10 = __builtin_amdgcn_mfma_f32_32x32x16_bf16(A1, B0, acc10, 0, 0, 0);
                acc11 = __builtin_amdgcn_mfma_f32_32x32x16_bf16(A1, B1, acc11, 0, 0, 0);
            }
        }
        if (more) {
            unsigned short* sN = sB[cur ^ 1];
#pragma unroll
            for (int s = 0; s < NLD; s++)
                if (sto[s] >= 0) *(uint4*)(sN + sto[s]) = pre[s];
            __syncthreads();
        }
    }
    unsigned short* ob = out + (size_t)b * H * W * Cout;
#pragma unroll
    for (int sm = 0; sm < 2; sm++) {
        v16f a0 = sm ? acc10 : acc00;
        v16f a1 = sm ? acc11 : acc01;
        const int cobase = coB + sm * 32 + 4 * kg;
        unsigned short* q0p = ob + ((size_t)((y0 + r0) * W + c0)) * Cout + cobase;
        unsigned short* q1p = ob + ((size_t)((y0 + r1) * W + c1)) * Cout + cobase;
#pragma unroll
        for (int r2 = 0; r2 < 4; r2++) {
            ushort4 q0, q1; float v;
            v = a0[4 * r2 + 0]; v = v > 0.f ? v : 0.f; q0.x = f2bf(v);
            v = a0[4 * r2 + 1]; v = v > 0.f ? v : 0.f; q0.y = f2bf(v);
            v = a0[4 * r2 + 2]; v = v > 0.f ? v : 0.f; q0.z = f2bf(v);
            v = a0[4 * r2 + 3]; v = v > 0.f ? v : 0.f; q0.w = f2bf(v);
            *(ushort4*)(q0p + 8 * r2) = q0;
            v = a1[4 * r2 + 0]; v = v > 0.f ? v : 0.f; q1.x = f2bf(v);
            v = a1[4 * r2 + 1]; v = v > 0.f ? v : 0.f; q1.y = f2bf(v);
            v = a1[4 * r2 + 2]; v = v > 0.f ? v : 0.f; q1.z = f2bf(v);
            v = a1[4 * r2 + 3]; v = v > 0.f ? v : 0.f; q1.w = f2bf(v);
            *(ushort4*)(q1p + 8 * r2) = q1;
        }
    }
}

// =====================================================================
// stride-2 deconv (k=3,p=1,op=1) as 4 parity convs on MFMA + ReLU.
// Same dbuf structure; simple inner loop.
// =====================================================================
template<int W, int TH, int NWN, int NWM, int LW>
__global__ __launch_bounds__(256) void deconv2_mfma(
        const unsigned short* __restrict__ X,
        const unsigned short* __restrict__ Wk,
        float* __restrict__ out, int Cin, int Cout, int Hin) {
    constexpr int ROWS = NWN * TH + 1;
    constexpr int NPIX = ROWS * (W + 1);
    constexpr int NIT = NPIX * 4;
    constexpr int NLD = (NIT + 255) / 256;
    __shared__ unsigned short sB[2][NPIX * 40];
    const int tid = threadIdx.x;
    const int lane = tid & 63, wv = tid >> 6;
    const int wm = wv / NWN, wn = wv % NWN;
    const int n = lane & 31, kg = lane >> 5;
    const int y0 = blockIdx.x * (NWN * TH);
    const int coB = (blockIdx.y * NWM + wm) * 64;
    const int b = blockIdx.z;
    const int Yl = wn * TH + (n >> LW);
    const int Xl = n & (W - 1);
    v16f zero = {};
    v16f acc[2][2][2];
#pragma unroll
    for (int i = 0; i < 2; i++)
#pragma unroll
        for (int j = 0; j < 2; j++)
#pragma unroll
            for (int s = 0; s < 2; s++) acc[i][j][s] = zero;
    const unsigned short* Xb = X + (size_t)b * Hin * W * Cin;
    const size_t cbStride = (size_t)(Cin >> 4) << 9;
    const size_t tStride  = (size_t)(Cout >> 5) * cbStride;
    const unsigned short* Af = Wk + (size_t)(coB >> 5) * cbStride + (lane << 3);
    const int PY[3] = {1, 0, 1}, DY[3] = {1, 0, 0};

    const unsigned short* ldp[NLD];
    int sto[NLD];
#pragma unroll
    for (int s = 0; s < NLD; s++) {
        int i = tid + s * 256;
        bool slot = (i < NIT);
        int pix = i >> 2, part = i & 3;
        int py_ = pix / (W + 1), px_ = pix - py_ * (W + 1);
        int gy = y0 + py_, gx = px_;
        bool ok = slot && gy < Hin && gx < W;
        ldp[s] = ok ? Xb + ((size_t)(gy * W + gx)) * Cin + part * 8 : nullptr;
        sto[s] = slot ? pix * 40 + part * 8 : -1;
    }

    uint4 pre[NLD];
#pragma unroll
    for (int s = 0; s < NLD; s++)
        pre[s] = ldp[s] ? *(const uint4*)(ldp[s]) : make_uint4(0u, 0u, 0u, 0u);
#pragma unroll
    for (int s = 0; s < NLD; s++)
        if (sto[s] >= 0) *(uint4*)(sB[0] + sto[s]) = pre[s];
    __syncthreads();

    const int NK = Cin >> 5;
    for (int kk = 0; kk < NK; kk++) {
        const int cur = kk & 1;
        const int ci0 = kk << 5;
        const bool more = (kk + 1 < NK);
        if (more) {
#pragma unroll
            for (int s = 0; s < NLD; s++)
                pre[s] = ldp[s] ? *(const uint4*)(ldp[s] + ci0 + 32)
                                : make_uint4(0u, 0u, 0u, 0u);
        }
        const unsigned short* sC = sB[cur];
#pragma unroll
        for (int ky = 0; ky < 3; ky++) {
#pragma unroll
            for (int kx = 0; kx < 3; kx++) {
                const int py = PY[ky], dy = DY[ky];
                const int px = PY[kx], dx = DY[kx];
                const int t = ky * 3 + kx;
                const int boff = ((Yl + dy) * (W + 1) + (Xl + dx)) * 40 + kg * 8;
#pragma unroll
                for (int kh = 0; kh < 2; kh++) {
                    const unsigned short* ap =
                        Af + (size_t)t * tStride + (size_t)(((ci0 >> 4) + kh) << 9);
                    v8s B  = *(const v8s*)(sC + boff + kh * 16);
                    v8s A0 = *(const v8s*)(ap);
                    v8s A1 = *(const v8s*)(ap + cbStride);
                    acc[py][px][0] = __builtin_amdgcn_mfma_f32_32x32x16_bf16(A0, B, acc[py][px][0], 0, 0, 0);
                    acc[py][px][1] = __builtin_amdgcn_mfma_f32_32x32x16_bf16(A1, B, acc[py][px][1], 0, 0, 0);
                }
            }
        }
        if (more) {
            unsigned short* sN = sB[cur ^ 1];
#pragma unroll
            for (int s = 0; s < NLD; s++)
                if (sto[s] >= 0) *(uint4*)(sN + sto[s]) = pre[s];
            __syncthreads();
        }
    }
    const int Wo = 2 * W, Ho = 2 * Hin;
    const int yin = y0 + Yl;
#pragma unroll
    for (int py = 0; py < 2; py++) {
        const int oy = 2 * yin + py;
#pragma unroll
        for (int sm = 0; sm < 2; sm++) {
            const int cobase = coB + sm * 32 + 4 * kg;
#pragma unroll
            for (int r = 0; r < 16; r++) {
                int co = cobase + (r & 3) + 8 * (r >> 2);
                float v0 = acc[py][0][sm][r]; v0 = v0 > 0.f ? v0 : 0.f;
                float v1 = acc[py][1][sm][r]; v1 = v1 > 0.f ? v1 : 0.f;
                *(float2*)(out + (((size_t)(b * Cout + co) * Ho + oy) * Wo + 2 * Xl)) =
                    make_float2(v0, v1);
            }
        }
    }
}

// =====================================================================
// Final stride-1 conv: Cout=3, tanh epilogue, fp32
// =====================================================================
__global__ __launch_bounds__(256) void conv_s1_c3_tanh_kernel(
        const float* __restrict__ in, const float* __restrict__ w,
        float* __restrict__ out, int Cin, int H, int W) {
    __shared__ float sIn[8][18][19];
    __shared__ float sW[8][3][9];
    const int tid = threadIdx.x;
    const int r = tid >> 4, c = tid & 15;
    const int ntx = W >> 4;
    const int tx0 = (blockIdx.x % ntx) << 4, ty0 = (blockIdx.x / ntx) << 4;
    const int b = blockIdx.z;
    const int hw = H * W;
    float acc[3] = {0.f, 0.f, 0.f};
    for (int ci0 = 0; ci0 < Cin; ci0 += 8) {
        for (int i = tid; i < 8 * 18 * 18; i += 256) {
            int ci = i / 324, rr = i % 324, ly = rr / 18, lx = rr % 18;
            int gy = ty0 + ly - 1, gx = tx0 + lx - 1;
            float v = 0.f;
            if (gy >= 0 && gy < H && gx >= 0 && gx < W)
                v = in[(size_t)(b * Cin + ci0 + ci) * hw + gy * W + gx];
            sIn[ci][ly][lx] = v;
        }
        for (int i = tid; i < 8 * 3 * 9; i += 256) {
            int ci = i / 27, rr = i % 27, co = rr / 9, k = rr % 9;
            sW[ci][co][k] = w[(size_t)((ci0 + ci) * 3 + co) * 9 + (8 - k)];
        }
        __syncthreads();
#pragma unroll
        for (int ci = 0; ci < 8; ci++) {
            float v00 = sIn[ci][r][c],     v01 = sIn[ci][r][c + 1],     v02 = sIn[ci][r][c + 2];
            float v10 = sIn[ci][r + 1][c], v11 = sIn[ci][r + 1][c + 1], v12 = sIn[ci][r + 1][c + 2];
            float v20 = sIn[ci][r + 2][c], v21 = sIn[ci][r + 2][c + 1], v22 = sIn[ci][r + 2][c + 2];
#pragma unroll
            for (int co = 0; co < 3; co++) {
                const float* wp = &sW[ci][co][0];
                acc[co] += v00 * wp[0] + v01 * wp[1] + v02 * wp[2]
                         + v10 * wp[3] + v11 * wp[4] + v12 * wp[5]
                         + v20 * wp[6] + v21 * wp[7] + v22 * wp[8];
            }
        }
        __syncthreads();
    }
#pragma unroll
    for (int co = 0; co < 3; co++)
        out[(size_t)(b * 3 + co) * hw + (ty0 + r) * W + tx0 + c] = tanhf(acc[co]);
}

// =====================================================================
// Host pipeline. d_out: out | feat_8 | feat_16 | feat_32.
// Full path (ws >= 98MiB), liveness-checked layout (MiB offsets):
//   A0[0,64) X8[64,65) Wk1[65,66) X16[66,98)      (X16 emitted by fusion)
//   h1b[0,16) Wk2[16,18.25) Wk3[18.25,19) t32[34,98)
//   ph2: Wk4/Wk5[0,0.45) X32[0.5,32.5) h2b[34,66) h3q[66,98) tq[0.5,2)
// =====================================================================
extern "C" void kernel_launch(void* const* d_in, const int* in_sizes, int n_in,
                              void* d_out, int out_size, void* d_ws, size_t ws_size,
                              hipStream_t stream) {
    const float* cont = (const float*)d_in[0];
    const float* kv0 = (const float*)d_in[1];
    const float* kh0 = (const float*)d_in[2];
    const float* m0  = (const float*)d_in[3];
    const float* kv1 = (const float*)d_in[4];
    const float* kh1 = (const float*)d_in[5];
    const float* m1  = (const float*)d_in[6];
    const float* kv2 = (const float*)d_in[7];
    const float* kh2 = (const float*)d_in[8];
    const float* m2  = (const float*)d_in[9];
    const float* kv3 = (const float*)d_in[10];
    const float* kh3 = (const float*)d_in[11];
    const float* m3  = (const float*)d_in[12];
    const float* w1  = (const float*)d_in[13];
    const float* w2  = (const float*)d_in[14];
    const float* w3  = (const float*)d_in[15];
    const float* w4  = (const float*)d_in[16];
    const float* w5  = (const float*)d_in[17];
    const float* w6  = (const float*)d_in[18];

    float* out = (float*)d_out;
    float* f8  = out + 1572864;
    float* f16 = out + 2097152;
    float* f32 = out + 18874368;

    char* ws = (char*)d_ws;

    if (ws_size >= (size_t)102760448) {
        // ---------------- full path: fused transposes ----------------
        float* A0 = (float*)ws;                                   // [0,64Mi)
        unsigned short* X8  = (unsigned short*)(ws + 67108864);   // [64,65)
        unsigned short* Wk1 = (unsigned short*)(ws + 68157440);   // [65,66)
        unsigned short* X16 = (unsigned short*)(ws + 69206016);   // [66,98)

        fusion2_kernel<3, 16><<<dim3(32, 4), 256, 0, stream>>>(
            cont, kv0, kh0, m0, f8, X8, 64, 8, 6);
        repack_w_frag<<<128, 256, 0, stream>>>(w1, Wk1, 64, 512, 0);
        deconv2_mfma<8, 4, 2, 2, 3><<<dim3(1, 4, 128), 256, 0, stream>>>(
            X8, Wk1, A0, 64, 512, 8);
        fusion2_kernel<4, 16><<<dim3(128, 32), 256, 0, stream>>>(
            A0, kv1, kh1, m1, f16, X16, 512, 16, 8);

        unsigned short* h1b = (unsigned short*)ws;                // [0,16) (A0 dead)
        unsigned short* Wk2 = (unsigned short*)(ws + 16777216);   // [16,18.25)
        unsigned short* Wk3 = (unsigned short*)(ws + 19136512);   // [18.25,19)
        float* t32 = (float*)(ws + 35651584);                     // [34,98) (X16 dead)
        repack_w_frag<<<512, 256, 0, stream>>>(w2, Wk2, 512, 256, 1);
        conv3x3_mfma<16, 8, 4><<<dim3(2, 2, 128), 256, 0, stream>>>(
            X16, Wk2, h1b, 512, 256, 16);
        repack_w_frag<<<128, 256, 0, stream>>>(w3, Wk3, 256, 128, 0);
        deconv2_mfma<16, 2, 2, 2, 4><<<dim3(4, 1, 128), 256, 0, stream>>>(
            h1b, Wk3, t32, 256, 128, 16);

        unsigned short* Wk4 = (unsigned short*)ws;                // [0,0.28)
        unsigned short* Wk5 = (unsigned short*)(ws + 294912);     // [0.28,0.43)
        unsigned short* X32 = (unsigned short*)(ws + 524288);     // [0.5,32.5)
        unsigned short* h2b = (unsigned short*)(ws + 35651584);   // [34,66) (t32 dead after fusion)
        float* h3q = (float*)(ws + 69206016);                     // [66,98)
        float* tq  = (float*)(ws + 524288);                       // [0.5,2) (X32 dead)
        repack_w_frag<<<64, 256, 0, stream>>>(w4, Wk4, 128, 128, 1);
        repack_w_frag<<<32, 256, 0, stream>>>(w5, Wk5, 128, 64, 0);
        fusion2_kernel<5, 16><<<dim3(512, 8), 256, 0, stream>>>(
            t32, kv2, kh2, m2, f32, X32, 128, 32, 10);
        conv3x3_mfma<32, 4, 5><<<dim3(8, 1, 128), 256, 0, stream>>>(
            X32, Wk4, h2b, 128, 128, 32);
        for (int q = 0; q < 4; q++) {
            size_t bo = (size_t)q * 32;
            deconv2_mfma<32, 1, 4, 1, 5><<<dim3(8, 1, 32), 256, 0, stream>>>(
                h2b + bo * 131072, Wk5, h3q, 128, 64, 32);
            conv_s1_c3_tanh_kernel<<<dim3(16, 1, 32), 256, 0, stream>>>(h3q, w6, tq, 64, 64, 64);
            fusion2_kernel<6, 3><<<dim3(512, 1), 256, 0, stream>>>(
                tq, kv3 + bo * 5 * 4096, kh3 + bo * 5 * 4096, m3 + bo * 4096,
                out + bo * 3 * 4096, nullptr, 3, 64, 12);
        }
    } else {
        // ---------------- fallback: explicit transposes ----------------
        float* A0 = (float*)ws;
        unsigned short* X8  = (unsigned short*)(ws + 67108864);
        unsigned short* Wk1 = (unsigned short*)(ws + 68157440);

        fusion2_kernel<3, 16><<<dim3(32, 4), 256, 0, stream>>>(
            cont, kv0, kh0, m0, f8, nullptr, 64, 8, 6);
        nchw_to_nhwc_bf16<<<dim3(8, 128), 256, 8 * 72 * 2, stream>>>(f8, X8, 64, 8, 8, 3, 5);
        repack_w_frag<<<128, 256, 0, stream>>>(w1, Wk1, 64, 512, 0);
        deconv2_mfma<8, 4, 2, 2, 3><<<dim3(1, 4, 128), 256, 0, stream>>>(
            X8, Wk1, A0, 64, 512, 8);
        fusion2_kernel<4, 16><<<dim3(128, 32), 256, 0, stream>>>(
            A0, kv1, kh1, m1, f16, nullptr, 512, 16, 8);

        unsigned short* X16 = (unsigned short*)ws;
        unsigned short* h1b = (unsigned short*)(ws + 67108864);
        unsigned short* Wk3 = (unsigned short*)(ws + 83886080);
        unsigned short* Wk2 = (unsigned short*)(ws + 84475904);
        nchw_to_nhwc_bf16<<<dim3(16, 128), 256, 16 * 520 * 2, stream>>>(
            f16, X16, 512, 16, 16, 4, 8);
        repack_w_frag<<<512, 256, 0, stream>>>(w2, Wk2, 512, 256, 1);
        conv3x3_mfma<16, 8, 4><<<dim3(2, 2, 128), 256, 0, stream>>>(
            X16, Wk2, h1b, 512, 256, 16);
        repack_w_frag<<<128, 256, 0, stream>>>(w3, Wk3, 256, 128, 0);
        float* t32 = (float*)ws;
        deconv2_mfma<16, 2, 2, 2, 4><<<dim3(4, 1, 128), 256, 0, stream>>>(
            h1b, Wk3, t32, 256, 128, 16);
        fusion2_kernel<5, 16><<<dim3(512, 8), 256, 0, stream>>>(
            t32, kv2, kh2, m2, f32, nullptr, 128, 32, 10);

        unsigned short* Wk4  = (unsigned short*)ws;
        unsigned short* Wk5  = (unsigned short*)(ws + 294912);
        unsigned short* X32q = (unsigned short*)(ws + 524288);
        unsigned short* h2b  = (unsigned short*)(ws + 8912896);
        float* h3q = (float*)(ws + 17301504);
        float* tq  = (float*)(ws + 50855936);
        repack_w_frag<<<64, 256, 0, stream>>>(w4, Wk4, 128, 128, 1);
        repack_w_frag<<<32, 256, 0, stream>>>(w5, Wk5, 128, 64, 0);
        for (int q = 0; q < 4; q++) {
            size_t bo = (size_t)q * 32;
            const float* f32q = f32 + bo * 128 * 1024;
            nchw_to_nhwc_bf16<<<dim3(32, 32), 256, 32 * 136 * 2, stream>>>(
                f32q, X32q, 128, 32, 32, 5, 6);
            conv3x3_mfma<32, 4, 5><<<dim3(8, 1, 32), 256, 0, stream>>>(
                X32q, Wk4, h2b, 128, 128, 32);
            deconv2_mfma<32, 1, 4, 1, 5><<<dim3(8, 1, 32), 256, 0, stream>>>(
                h2b, Wk5, h3q, 128, 64, 32);
            conv_s1_c3_tanh_kernel<<<dim3(16, 1, 32), 256, 0, stream>>>(h3q, w6, tq, 64, 64, 64);
            fusion2_kernel<6, 3><<<dim3(512, 1), 256, 0, stream>>>(
                tq, kv3 + bo * 5 * 4096, kh3 + bo * 5 * 4096, m3 + bo * 4096,
                out + bo * 3 * 4096, nullptr, 3, 64, 12);
        }
    }
}